// Round 2
// baseline (1064.077 us; speedup 1.0000x reference)
//
#include <hip/hip_runtime.h>
#include <vector>
#include <algorithm>
#include <cstdint>
#include <cstring>
#include <cmath>

// ===================== host-side JAX threefry replication =====================
// Replicates jax.random.permutation(jax.random.key(seed), n) with
// jax_threefry_partitionable=True (default since JAX 0.4.36):
//   - split: child key i = full cipher output of (key, 64-bit count i)
//   - random_bits(32): bits[i] = w0 ^ w1 of cipher(key, 64-bit count i)
//   - _shuffle: ceil(3*ln(n)/ln(2^32)) rounds of stable sort by bits
static inline uint32_t tf_rotl(uint32_t x, int r) { return (x << r) | (x >> (32 - r)); }

static void tf2x32(uint32_t k0, uint32_t k1, uint32_t x0, uint32_t x1,
                   uint32_t* o0, uint32_t* o1) {
  uint32_t ks2 = k0 ^ k1 ^ 0x1BD11BDAu;
  uint32_t v0 = x0 + k0, v1 = x1 + k1;
  static const int R0[4] = {13, 15, 26, 6}, R1[4] = {17, 29, 16, 24};
#define RND4(R) do { for (int i_ = 0; i_ < 4; ++i_) { v0 += v1; v1 = tf_rotl(v1, R[i_]); v1 ^= v0; } } while (0)
  RND4(R0); v0 += k1;  v1 += ks2 + 1u;
  RND4(R1); v0 += ks2; v1 += k0 + 2u;
  RND4(R0); v0 += k0;  v1 += k1 + 3u;
  RND4(R1); v0 += k1;  v1 += ks2 + 4u;
  RND4(R0); v0 += ks2; v1 += k0 + 5u;
#undef RND4
  *o0 = v0; *o1 = v1;
}

static void jax_permutation(uint32_t seed, int n, int rounds, int* x) {
  uint32_t k0 = 0u, k1 = seed;  // jax.random.key(seed) -> data [0, seed]
  for (int i = 0; i < n; ++i) x[i] = i;
  std::vector<uint32_t> bits(n);
  std::vector<int> ord(n), xn(n);
  for (int r = 0; r < rounds; ++r) {
    uint32_t nk0, nk1, sk0, sk1;
    tf2x32(k0, k1, 0u, 0u, &nk0, &nk1);  // carry key = cipher(key, count 0)
    tf2x32(k0, k1, 0u, 1u, &sk0, &sk1);  // subkey    = cipher(key, count 1)
    for (int i = 0; i < n; ++i) {
      uint32_t h, l;
      tf2x32(sk0, sk1, 0u, (uint32_t)i, &h, &l);
      bits[i] = h ^ l;
    }
    for (int i = 0; i < n; ++i) ord[i] = i;
    std::stable_sort(ord.begin(), ord.end(),
                     [&](int a, int b) { return bits[a] < bits[b]; });
    for (int i = 0; i < n; ++i) xn[i] = x[ord[i]];
    memcpy(x, xn.data(), (size_t)n * sizeof(int));
    k0 = nk0; k1 = nk1;
  }
}

// ===================== device kernels =====================
#define NEI 20

// sanitize: NaN -> 0, clamp to +-1e4. No-op on well-formed inputs; makes a
// dtype-mismatch failure finite (diagnostic) instead of NaN.
__device__ __forceinline__ float san(float v) {
  v = (v != v) ? 0.0f : v;
  return fmaxf(-1e4f, fminf(v, 1e4f));
}

__global__ void k_san_copy(const float* __restrict__ in, float* __restrict__ out, int n) {
  int i = blockIdx.x * blockDim.x + threadIdx.x;
  if (i < n) out[i] = san(in[i]);
}

// column-normalize a (3, E) direction matrix
__global__ void k_norm_dirs(const float* __restrict__ d, float* __restrict__ sd, int E) {
  int e = blockIdx.x * blockDim.x + threadIdx.x;
  if (e >= E) return;
  float a = san(d[e]);
  float b = san(d[E + e]);
  float c = san(d[2 * E + e]);
  float nrm = sqrtf(a * a + b * b + c * c);
  float m = fmaxf(nrm, 1e-12f);
  sd[e] = a / m; sd[E + e] = b / m; sd[2 * E + e] = c / m;
}

// KNN: one block per (b,i) row. Keys (ordered_float(dist)<<32 | j) in LDS,
// 21 rounds of block-wide min selection => exact lax.top_k tie semantics.
__global__ __launch_bounds__(256) void k_knn(const float* __restrict__ verts,
                                             int* __restrict__ nidx, int V) {
  int row = blockIdx.x;
  int b = row / V, i = row % V;
  const float* vb = verts + (size_t)b * V * 3;
  extern __shared__ unsigned long long keys[];
  __shared__ unsigned long long red[8];
  float xi = vb[3 * i], yi = vb[3 * i + 1], zi = vb[3 * i + 2];
  float sqi = xi * xi + yi * yi + zi * zi;
  for (int j = threadIdx.x; j < V; j += blockDim.x) {
    float xj = vb[3 * j], yj = vb[3 * j + 1], zj = vb[3 * j + 2];
    float sqj = xj * xj + yj * yj + zj * zj;
    float dot = xi * xj + yi * yj + zi * zj;
    float dd = (sqi + sqj) - 2.0f * dot;
    unsigned u = __float_as_uint(dd);
    u ^= (u & 0x80000000u) ? 0xFFFFFFFFu : 0x80000000u;  // total-order map
    keys[j] = (((unsigned long long)u) << 32) | (unsigned)j;
  }
  __syncthreads();
  unsigned long long last = 0ULL;
  int nw = blockDim.x >> 6;
  for (int r = 0; r < 21; ++r) {
    unsigned long long mk = ~0ULL;
    for (int j = threadIdx.x; j < V; j += blockDim.x) {
      unsigned long long k = keys[j];
      if (k > last && k < mk) mk = k;
    }
    for (int o = 32; o > 0; o >>= 1) {
      unsigned long long t = __shfl_down(mk, o);
      if (t < mk) mk = t;
    }
    if ((threadIdx.x & 63) == 0) red[threadIdx.x >> 6] = mk;
    __syncthreads();
    if (threadIdx.x == 0) {
      unsigned long long mm = red[0];
      for (int w = 1; w < nw; ++w) if (red[w] < mm) mm = red[w];
      red[0] = mm;
    }
    __syncthreads();
    mk = red[0];
    if (r > 0 && threadIdx.x == 0) nidx[(size_t)row * NEI + (r - 1)] = (int)(mk & 0xFFFFFFFFu);
    last = mk;
    __syncthreads();
  }
}

// conv_surface: C=32, E=128. One block (128 thr) per (b,v).
__global__ __launch_bounds__(128) void k_conv_surface(const float* __restrict__ verts,
                                                      const int* __restrict__ nidx,
                                                      const float* __restrict__ sd,
                                                      float* __restrict__ fm, int V) {
  int row = blockIdx.x;
  int b = row / V, v = row % V;
  const float* vb = verts + (size_t)b * V * 3;
  __shared__ float nd[60];
  __shared__ float mcol[128];
  int tid = threadIdx.x;
  if (tid < NEI) {
    int j = nidx[(size_t)row * NEI + tid];
    float dx = vb[3 * j] - vb[3 * v];
    float dy = vb[3 * j + 1] - vb[3 * v + 1];
    float dz = vb[3 * j + 2] - vb[3 * v + 2];
    float nrm = sqrtf(dx * dx + dy * dy + dz * dz);
    float m = fmaxf(nrm, 1e-12f);
    nd[tid * 3] = dx / m; nd[tid * 3 + 1] = dy / m; nd[tid * 3 + 2] = dz / m;
  }
  __syncthreads();
  {
    int e = tid;
    float s0 = sd[e], s1 = sd[128 + e], s2 = sd[256 + e];
    float me = 0.0f;  // relu'd thetas are >= 0
    for (int n = 0; n < NEI; ++n) {
      float th = nd[3 * n] * s0 + nd[3 * n + 1] * s1 + nd[3 * n + 2] * s2;
      th = fmaxf(th, 0.0f);
      me = fmaxf(me, th);
    }
    mcol[e] = me;
  }
  __syncthreads();
  if (tid < 32) {
    float o = mcol[tid] + mcol[32 + tid] + mcol[64 + tid] + mcol[96 + tid];
    o = fmaxf(o, 0.0f);
    fm[(size_t)row * 32 + tid] = o;
  }
}

// fp32 tiled GEMM: C[M,N] = A[M,K] * W[K,N] + bias[N]
__global__ __launch_bounds__(256) void k_gemm_bias(const float* __restrict__ A,
                                                   const float* __restrict__ W,
                                                   const float* __restrict__ bias,
                                                   float* __restrict__ Cm,
                                                   int M, int N, int K) {
  __shared__ float As[16][65];
  __shared__ float Bs[16][65];
  int n0 = blockIdx.x * 64, m0 = blockIdx.y * 64;
  int tx = threadIdx.x & 15, ty = threadIdx.x >> 4;
  float acc[4][4] = {};
  for (int k0 = 0; k0 < K; k0 += 16) {
    for (int t = threadIdx.x; t < 1024; t += 256) {
      int mm = t >> 4, kk = t & 15;
      int m = m0 + mm;
      As[kk][mm] = (m < M) ? A[(size_t)m * K + (k0 + kk)] : 0.0f;
    }
    for (int t = threadIdx.x; t < 1024; t += 256) {
      int kk = t >> 6, nn = t & 63;
      int n = n0 + nn;
      Bs[kk][nn] = (n < N) ? san(W[(size_t)(k0 + kk) * N + n]) : 0.0f;
    }
    __syncthreads();
#pragma unroll
    for (int kk = 0; kk < 16; ++kk) {
      float a[4], bb[4];
#pragma unroll
      for (int i = 0; i < 4; ++i) { a[i] = As[kk][(ty << 2) + i]; bb[i] = Bs[kk][(tx << 2) + i]; }
#pragma unroll
      for (int i = 0; i < 4; ++i)
#pragma unroll
        for (int j = 0; j < 4; ++j) acc[i][j] += a[i] * bb[j];
    }
    __syncthreads();
  }
  for (int i = 0; i < 4; ++i)
    for (int j = 0; j < 4; ++j) {
      int m = m0 + (ty << 2) + i, n = n0 + (tx << 2) + j;
      if (m < M && n < N) Cm[(size_t)m * N + n] = acc[i][j] + san(bias[n]);
    }
}

// conv layer: out[c] = f[row][c] + sum_s max_n relu(nd_n . sd_e) * f[j_n][C+e], e=s*C+c
__global__ __launch_bounds__(256) void k_conv_layer(const float* __restrict__ f,
                                                    const float* __restrict__ verts,
                                                    const int* __restrict__ nidx,
                                                    const float* __restrict__ sd,
                                                    float* __restrict__ outf,
                                                    float* __restrict__ outt,
                                                    int V, int C, int relu_out, int transpose_out) {
  int row = blockIdx.x;
  int b = row / V, v = row % V;
  int E = 4 * C;
  extern __shared__ float sm[];
  float* mcol = sm;           // E floats
  float* nd = sm + E;         // 60 floats
  int* jr = (int*)(nd + 60);  // 20 ints
  int tid = threadIdx.x;
  const float* vb = verts + (size_t)b * V * 3;
  if (tid < NEI) {
    int j = nidx[(size_t)row * NEI + tid];
    jr[tid] = j;
    float dx = vb[3 * j] - vb[3 * v];
    float dy = vb[3 * j + 1] - vb[3 * v + 1];
    float dz = vb[3 * j + 2] - vb[3 * v + 2];
    float nrm = sqrtf(dx * dx + dy * dy + dz * dz);
    float m = fmaxf(nrm, 1e-12f);
    nd[tid * 3] = dx / m; nd[tid * 3 + 1] = dy / m; nd[tid * 3 + 2] = dz / m;
  }
  __syncthreads();
  size_t fb = (size_t)b * V;
  int fivec = 5 * C;
  for (int e = tid; e < E; e += blockDim.x) {
    float s0 = sd[e], s1 = sd[E + e], s2 = sd[2 * E + e];
    float me = -INFINITY;
    for (int n = 0; n < NEI; ++n) {
      float th = nd[3 * n] * s0 + nd[3 * n + 1] * s1 + nd[3 * n + 2] * s2;
      th = fmaxf(th, 0.0f);
      float fv = f[(fb + jr[n]) * (size_t)fivec + C + e];
      me = fmaxf(me, th * fv);
    }
    mcol[e] = me;
  }
  __syncthreads();
  for (int c = tid; c < C; c += blockDim.x) {
    float o = f[(size_t)row * fivec + c] + mcol[c] + mcol[C + c] + mcol[2 * C + c] + mcol[3 * C + c];
    if (relu_out) o = fmaxf(o, 0.0f);
    if (transpose_out) outt[((size_t)b * C + c) * V + v] = o;
    else outf[(size_t)row * C + c] = o;
  }
}

__global__ void k_pool(const float* __restrict__ fm, const int* __restrict__ nidx,
                       const int* __restrict__ sel, float* __restrict__ outp,
                       int Vin, int Vout, int C) {
  int t = blockIdx.x * blockDim.x + threadIdx.x;
  int total = 4 * Vout * C;
  if (t >= total) return;
  int c = t % C;
  int p = (t / C) % Vout;
  int b = t / (C * Vout);
  int sv = sel[p];
  const int* ir = nidx + ((size_t)b * Vin + sv) * NEI;
  float m = -INFINITY;
  for (int n = 0; n < NEI; ++n)
    m = fmaxf(m, fm[((size_t)b * Vin + ir[n]) * C + c]);
  outp[((size_t)b * Vout + p) * C + c] = m;
}

__global__ void k_sel_verts(const float* __restrict__ vin, const int* __restrict__ sel,
                            float* __restrict__ vout, int Vin, int Vout) {
  int t = blockIdx.x * blockDim.x + threadIdx.x;
  int total = 4 * Vout * 3;
  if (t >= total) return;
  int d = t % 3;
  int p = (t / 3) % Vout;
  int b = t / (3 * Vout);
  vout[((size_t)b * Vout + p) * 3 + d] = vin[((size_t)b * Vin + sel[p]) * 3 + d];
}

// ===================== launch =====================
extern "C" void kernel_launch(void* const* d_in, const int* in_sizes, int n_in,
                              void* d_out, int out_size, void* d_ws, size_t ws_size,
                              hipStream_t stream) {
  (void)in_sizes; (void)n_in; (void)out_size; (void)ws_size;
  const int B = 4, V1 = 4096, V2 = 1024, V3 = 256;

  const float* vin   = (const float*)d_in[0];
  const float* dirs0 = (const float*)d_in[1];
  const float* W1 = (const float*)d_in[2];
  const float* b1 = (const float*)d_in[3];
  const float* D1 = (const float*)d_in[4];
  const float* W2 = (const float*)d_in[5];
  const float* b2 = (const float*)d_in[6];
  const float* D2 = (const float*)d_in[7];
  const float* W3 = (const float*)d_in[8];
  const float* b3 = (const float*)d_in[9];
  const float* D3 = (const float*)d_in[10];
  const float* W4 = (const float*)d_in[11];
  const float* b4 = (const float*)d_in[12];
  const float* D4 = (const float*)d_in[13];
  float* out = (float*)d_out;

  // workspace layout (lifetime-overlapped arenas; total ~30 MB)
  char* ws = (char*)d_ws;
  size_t off = 0;
  auto alloc = [&](size_t bytes) -> char* {
    char* p = ws + off;
    off = (off + bytes + 255) & ~(size_t)255;
    return p;
  };
  int* sel1 = (int*)alloc((size_t)V2 * 4);
  int* sel2 = (int*)alloc((size_t)V3 * 4);
  float* verts1 = (float*)alloc((size_t)B * V1 * 3 * 4);
  float* verts2 = (float*)alloc((size_t)B * V2 * 3 * 4);
  float* verts3 = (float*)alloc((size_t)B * V3 * 3 * 4);
  int* idx1 = (int*)alloc((size_t)B * V1 * NEI * 4);
  int* idx2 = (int*)alloc((size_t)B * V2 * NEI * 4);
  int* idx3 = (int*)alloc((size_t)B * V3 * NEI * 4);
  float* sd0 = (float*)alloc(3 * 128 * 4);
  float* sd1 = (float*)alloc(3 * 256 * 4);
  float* sd2 = (float*)alloc(3 * 512 * 4);
  float* sd3 = (float*)alloc(3 * 1024 * 4);
  float* sd4 = (float*)alloc(3 * 4096 * 4);
  // arenas: fm0/fm2 (both 2MB), fm1/fm3 (both 4MB), fm1p/fm3p (both 1MB)
  float* bufA = (float*)alloc((size_t)B * V1 * 32 * 4);
  float* bufB = (float*)alloc((size_t)B * V1 * 64 * 4);
  float* bufC = (float*)alloc((size_t)B * V2 * 64 * 4);
  float* fbuf = (float*)alloc((size_t)B * V1 * 320 * 4);  // per-layer f (max 21MB)
  float* fm0 = bufA, *fm2 = bufA;
  float* fm1 = bufB, *fm3 = bufB;
  float* fm1p = bufC, *fm3p = bufC;

  // host permutations (deterministic; same values every call)
  static int perm1[4096];
  static int perm2[1024];
  static int selh[1280];
  jax_permutation(42u, 4096, 2, perm1);
  jax_permutation(43u, 1024, 1, perm2);
  memcpy(selh, perm1, 1024 * sizeof(int));
  memcpy(selh + 1024, perm2, 256 * sizeof(int));
  hipMemcpyAsync(sel1, selh, 1024 * sizeof(int), hipMemcpyHostToDevice, stream);
  hipMemcpyAsync(sel2, selh + 1024, 256 * sizeof(int), hipMemcpyHostToDevice, stream);

  // 1. sanitize vertices
  {
    int n = B * V1 * 3;
    k_san_copy<<<(n + 255) / 256, 256, 0, stream>>>(vin, verts1, n);
  }
  // 2. normalize all direction matrices
  k_norm_dirs<<<1, 128, 0, stream>>>(dirs0, sd0, 128);
  k_norm_dirs<<<1, 256, 0, stream>>>(D1, sd1, 256);
  k_norm_dirs<<<2, 256, 0, stream>>>(D2, sd2, 512);
  k_norm_dirs<<<4, 256, 0, stream>>>(D3, sd3, 1024);
  k_norm_dirs<<<16, 256, 0, stream>>>(D4, sd4, 4096);
  // 3. knn level 1
  k_knn<<<B * V1, 256, (size_t)V1 * 8, stream>>>(verts1, idx1, V1);
  // 4. surface conv -> fm0 (B*V1 x 32)
  k_conv_surface<<<B * V1, 128, 0, stream>>>(verts1, idx1, sd0, fm0, V1);
  // 5. layer1: f = fm0 @ W1 + b1 (16384x320), conv C=64 -> fm1
  k_gemm_bias<<<dim3(5, 256), 256, 0, stream>>>(fm0, W1, b1, fbuf, B * V1, 320, 32);
  k_conv_layer<<<B * V1, 256, (4 * 64 + 80) * 4, stream>>>(fbuf, verts1, idx1, sd1, fm1, nullptr, V1, 64, 1, 0);
  // 6. pool1 -> fm1p (B*V2 x 64), verts2
  {
    int total = B * V2 * 64;
    k_pool<<<(total + 255) / 256, 256, 0, stream>>>(fm1, idx1, sel1, fm1p, V1, V2, 64);
    int tv = B * V2 * 3;
    k_sel_verts<<<(tv + 255) / 256, 256, 0, stream>>>(verts1, sel1, verts2, V1, V2);
  }
  // 7. knn level 2
  k_knn<<<B * V2, 256, (size_t)V2 * 8, stream>>>(verts2, idx2, V2);
  // 8. layer2: f = fm1p @ W2 + b2 (4096x640), conv C=128 -> fm2
  k_gemm_bias<<<dim3(10, 64), 256, 0, stream>>>(fm1p, W2, b2, fbuf, B * V2, 640, 64);
  k_conv_layer<<<B * V2, 256, (4 * 128 + 80) * 4, stream>>>(fbuf, verts2, idx2, sd2, fm2, nullptr, V2, 128, 1, 0);
  // 9. layer3: f = fm2 @ W3 + b3 (4096x1280), conv C=256 -> fm3
  k_gemm_bias<<<dim3(20, 64), 256, 0, stream>>>(fm2, W3, b3, fbuf, B * V2, 1280, 128);
  k_conv_layer<<<B * V2, 256, (4 * 256 + 80) * 4, stream>>>(fbuf, verts2, idx2, sd3, fm3, nullptr, V2, 256, 1, 0);
  // 10. pool2 -> fm3p (B*V3 x 256), verts3
  {
    int total = B * V3 * 256;
    k_pool<<<(total + 255) / 256, 256, 0, stream>>>(fm3, idx2, sel2, fm3p, V2, V3, 256);
    int tv = B * V3 * 3;
    k_sel_verts<<<(tv + 255) / 256, 256, 0, stream>>>(verts2, sel2, verts3, V2, V3);
  }
  // 11. knn level 3
  k_knn<<<B * V3, 256, (size_t)V3 * 8, stream>>>(verts3, idx3, V3);
  // 12. layer4: f = fm3p @ W4 + b4 (1024x5120), conv C=1024, no relu,
  //     write transposed into d_out (shape (4,1024,256,1))
  k_gemm_bias<<<dim3(80, 16), 256, 0, stream>>>(fm3p, W4, b4, fbuf, B * V3, 5120, 256);
  k_conv_layer<<<B * V3, 256, (4 * 1024 + 80) * 4, stream>>>(fbuf, verts3, idx3, sd4, nullptr, out, V3, 1024, 0, 1);
}

// Round 3
// 725.363 us; speedup vs baseline: 1.4670x; 1.4670x over previous
//
#include <hip/hip_runtime.h>
#include <vector>
#include <algorithm>
#include <cstdint>
#include <cstring>
#include <cmath>

// ===================== host-side JAX threefry replication =====================
static inline uint32_t tf_rotl(uint32_t x, int r) { return (x << r) | (x >> (32 - r)); }

static void tf2x32(uint32_t k0, uint32_t k1, uint32_t x0, uint32_t x1,
                   uint32_t* o0, uint32_t* o1) {
  uint32_t ks2 = k0 ^ k1 ^ 0x1BD11BDAu;
  uint32_t v0 = x0 + k0, v1 = x1 + k1;
  static const int R0[4] = {13, 15, 26, 6}, R1[4] = {17, 29, 16, 24};
#define RND4(R) do { for (int i_ = 0; i_ < 4; ++i_) { v0 += v1; v1 = tf_rotl(v1, R[i_]); v1 ^= v0; } } while (0)
  RND4(R0); v0 += k1;  v1 += ks2 + 1u;
  RND4(R1); v0 += ks2; v1 += k0 + 2u;
  RND4(R0); v0 += k0;  v1 += k1 + 3u;
  RND4(R1); v0 += k1;  v1 += ks2 + 4u;
  RND4(R0); v0 += ks2; v1 += k0 + 5u;
#undef RND4
  *o0 = v0; *o1 = v1;
}

static void jax_permutation(uint32_t seed, int n, int rounds, int* x) {
  uint32_t k0 = 0u, k1 = seed;
  for (int i = 0; i < n; ++i) x[i] = i;
  std::vector<uint32_t> bits(n);
  std::vector<int> ord(n), xn(n);
  for (int r = 0; r < rounds; ++r) {
    uint32_t nk0, nk1, sk0, sk1;
    tf2x32(k0, k1, 0u, 0u, &nk0, &nk1);
    tf2x32(k0, k1, 0u, 1u, &sk0, &sk1);
    for (int i = 0; i < n; ++i) {
      uint32_t h, l;
      tf2x32(sk0, sk1, 0u, (uint32_t)i, &h, &l);
      bits[i] = h ^ l;
    }
    for (int i = 0; i < n; ++i) ord[i] = i;
    std::stable_sort(ord.begin(), ord.end(),
                     [&](int a, int b) { return bits[a] < bits[b]; });
    for (int i = 0; i < n; ++i) xn[i] = x[ord[i]];
    memcpy(x, xn.data(), (size_t)n * sizeof(int));
    k0 = nk0; k1 = nk1;
  }
}

// ===================== device kernels =====================
#define NEI 20

__device__ __forceinline__ float san(float v) {
  v = (v != v) ? 0.0f : v;
  return fmaxf(-1e4f, fminf(v, 1e4f));
}

__global__ void k_san_copy(const float* __restrict__ in, float* __restrict__ out, int n) {
  int i = blockIdx.x * blockDim.x + threadIdx.x;
  if (i < n) out[i] = san(in[i]);
}

__global__ void k_norm_dirs(const float* __restrict__ d, float* __restrict__ sd, int E) {
  int e = blockIdx.x * blockDim.x + threadIdx.x;
  if (e >= E) return;
  float a = san(d[e]);
  float b = san(d[E + e]);
  float c = san(d[2 * E + e]);
  float nrm = sqrtf(a * a + b * b + c * c);
  float m = fmaxf(nrm, 1e-12f);
  sd[e] = a / m; sd[E + e] = b / m; sd[2 * E + e] = c / m;
}

// KNN v2: one block (256 thr) per query row. CAND = V/256 keys per thread held in
// REGISTERS; 21 rounds of (register scan w/ filter -> wave shuffle-min -> 4-slot
// LDS cross-wave min). One barrier/round, parity-double-buffered slots.
// Keys (ordered_float(dist)<<32 | j) are unique => exact lax.top_k tie semantics.
template <int CAND>
__global__ __launch_bounds__(256) void k_knn2(const float* __restrict__ verts,
                                              int* __restrict__ nidx, int V) {
  int row = blockIdx.x;
  int b = row / V, i = row % V;
  const float* vb = verts + (size_t)b * V * 3;
  __shared__ unsigned long long red[2][4];
  int tid = threadIdx.x;
  float xi = vb[3 * i], yi = vb[3 * i + 1], zi = vb[3 * i + 2];
  float sqi = xi * xi + yi * yi + zi * zi;
  unsigned long long key[CAND];
#pragma unroll
  for (int c = 0; c < CAND; ++c) {
    int j = c * 256 + tid;
    float xj = vb[3 * j], yj = vb[3 * j + 1], zj = vb[3 * j + 2];
    float sqj = xj * xj + yj * yj + zj * zj;
    float dot = xi * xj + yi * yj + zi * zj;
    float dd = (sqi + sqj) - 2.0f * dot;
    unsigned u = __float_as_uint(dd);
    u ^= (u & 0x80000000u) ? 0xFFFFFFFFu : 0x80000000u;  // total-order map
    key[c] = (((unsigned long long)u) << 32) | (unsigned)j;
  }
  unsigned long long last = 0ULL;  // all real keys are > 0
  for (int r = 0; r < 21; ++r) {
    unsigned long long m = ~0ULL;  // sentinel; real keys have low bits < 4096
#pragma unroll
    for (int c = 0; c < CAND; ++c)
      if (key[c] > last && key[c] < m) m = key[c];
    for (int o = 32; o > 0; o >>= 1) {
      unsigned long long t = __shfl_down(m, o);
      if (t < m) m = t;
    }
    if ((tid & 63) == 0) red[r & 1][tid >> 6] = m;
    __syncthreads();
    unsigned long long bm = red[r & 1][0];
#pragma unroll
    for (int w = 1; w < 4; ++w) {
      unsigned long long t = red[r & 1][w];
      if (t < bm) bm = t;
    }
    if (r > 0 && tid == 0) nidx[(size_t)row * NEI + (r - 1)] = (int)(bm & 0xFFFFFFFFu);
    last = bm;
  }
}

// conv_surface: C=32, E=128. One block (128 thr) per (b,v).
__global__ __launch_bounds__(128) void k_conv_surface(const float* __restrict__ verts,
                                                      const int* __restrict__ nidx,
                                                      const float* __restrict__ sd,
                                                      float* __restrict__ fm, int V) {
  int row = blockIdx.x;
  int b = row / V, v = row % V;
  const float* vb = verts + (size_t)b * V * 3;
  __shared__ float nd[60];
  __shared__ float mcol[128];
  int tid = threadIdx.x;
  if (tid < NEI) {
    int j = nidx[(size_t)row * NEI + tid];
    float dx = vb[3 * j] - vb[3 * v];
    float dy = vb[3 * j + 1] - vb[3 * v + 1];
    float dz = vb[3 * j + 2] - vb[3 * v + 2];
    float nrm = sqrtf(dx * dx + dy * dy + dz * dz);
    float m = fmaxf(nrm, 1e-12f);
    nd[tid * 3] = dx / m; nd[tid * 3 + 1] = dy / m; nd[tid * 3 + 2] = dz / m;
  }
  __syncthreads();
  {
    int e = tid;
    float s0 = sd[e], s1 = sd[128 + e], s2 = sd[256 + e];
    float me = 0.0f;
    for (int n = 0; n < NEI; ++n) {
      float th = nd[3 * n] * s0 + nd[3 * n + 1] * s1 + nd[3 * n + 2] * s2;
      th = fmaxf(th, 0.0f);
      me = fmaxf(me, th);
    }
    mcol[e] = me;
  }
  __syncthreads();
  if (tid < 32) {
    float o = mcol[tid] + mcol[32 + tid] + mcol[64 + tid] + mcol[96 + tid];
    o = fmaxf(o, 0.0f);
    fm[(size_t)row * 32 + tid] = o;
  }
}

// fp32 tiled GEMM: C[M,N] = A[M,K] * W[K,N] + bias[N]
__global__ __launch_bounds__(256) void k_gemm_bias(const float* __restrict__ A,
                                                   const float* __restrict__ W,
                                                   const float* __restrict__ bias,
                                                   float* __restrict__ Cm,
                                                   int M, int N, int K) {
  __shared__ float As[16][65];
  __shared__ float Bs[16][65];
  int n0 = blockIdx.x * 64, m0 = blockIdx.y * 64;
  int tx = threadIdx.x & 15, ty = threadIdx.x >> 4;
  float acc[4][4] = {};
  for (int k0 = 0; k0 < K; k0 += 16) {
    for (int t = threadIdx.x; t < 1024; t += 256) {
      int mm = t >> 4, kk = t & 15;
      int m = m0 + mm;
      As[kk][mm] = (m < M) ? A[(size_t)m * K + (k0 + kk)] : 0.0f;
    }
    for (int t = threadIdx.x; t < 1024; t += 256) {
      int kk = t >> 6, nn = t & 63;
      int n = n0 + nn;
      Bs[kk][nn] = (n < N) ? san(W[(size_t)(k0 + kk) * N + n]) : 0.0f;
    }
    __syncthreads();
#pragma unroll
    for (int kk = 0; kk < 16; ++kk) {
      float a[4], bb[4];
#pragma unroll
      for (int i = 0; i < 4; ++i) { a[i] = As[kk][(ty << 2) + i]; bb[i] = Bs[kk][(tx << 2) + i]; }
#pragma unroll
      for (int i = 0; i < 4; ++i)
#pragma unroll
        for (int j = 0; j < 4; ++j) acc[i][j] += a[i] * bb[j];
    }
    __syncthreads();
  }
  for (int i = 0; i < 4; ++i)
    for (int j = 0; j < 4; ++j) {
      int m = m0 + (ty << 2) + i, n = n0 + (tx << 2) + j;
      if (m < M && n < N) Cm[(size_t)m * N + n] = acc[i][j] + san(bias[n]);
    }
}

// conv layer: out[c] = f[row][c] + sum_s max_n relu(nd_n . sd_e) * f[j_n][C+e], e=s*C+c
__global__ __launch_bounds__(256) void k_conv_layer(const float* __restrict__ f,
                                                    const float* __restrict__ verts,
                                                    const int* __restrict__ nidx,
                                                    const float* __restrict__ sd,
                                                    float* __restrict__ outf,
                                                    float* __restrict__ outt,
                                                    int V, int C, int relu_out, int transpose_out) {
  int row = blockIdx.x;
  int b = row / V, v = row % V;
  int E = 4 * C;
  extern __shared__ float sm[];
  float* mcol = sm;           // E floats
  float* nd = sm + E;         // 60 floats
  int* jr = (int*)(nd + 60);  // 20 ints
  int tid = threadIdx.x;
  const float* vb = verts + (size_t)b * V * 3;
  if (tid < NEI) {
    int j = nidx[(size_t)row * NEI + tid];
    jr[tid] = j;
    float dx = vb[3 * j] - vb[3 * v];
    float dy = vb[3 * j + 1] - vb[3 * v + 1];
    float dz = vb[3 * j + 2] - vb[3 * v + 2];
    float nrm = sqrtf(dx * dx + dy * dy + dz * dz);
    float m = fmaxf(nrm, 1e-12f);
    nd[tid * 3] = dx / m; nd[tid * 3 + 1] = dy / m; nd[tid * 3 + 2] = dz / m;
  }
  __syncthreads();
  size_t fb = (size_t)b * V;
  int fivec = 5 * C;
  for (int e = tid; e < E; e += blockDim.x) {
    float s0 = sd[e], s1 = sd[E + e], s2 = sd[2 * E + e];
    float me = -INFINITY;
    for (int n = 0; n < NEI; ++n) {
      float th = nd[3 * n] * s0 + nd[3 * n + 1] * s1 + nd[3 * n + 2] * s2;
      th = fmaxf(th, 0.0f);
      float fv = f[(fb + jr[n]) * (size_t)fivec + C + e];
      me = fmaxf(me, th * fv);
    }
    mcol[e] = me;
  }
  __syncthreads();
  for (int c = tid; c < C; c += blockDim.x) {
    float o = f[(size_t)row * fivec + c] + mcol[c] + mcol[C + c] + mcol[2 * C + c] + mcol[3 * C + c];
    if (relu_out) o = fmaxf(o, 0.0f);
    if (transpose_out) outt[((size_t)b * C + c) * V + v] = o;
    else outf[(size_t)row * C + c] = o;
  }
}

__global__ void k_pool(const float* __restrict__ fm, const int* __restrict__ nidx,
                       const int* __restrict__ sel, float* __restrict__ outp,
                       int Vin, int Vout, int C) {
  int t = blockIdx.x * blockDim.x + threadIdx.x;
  int total = 4 * Vout * C;
  if (t >= total) return;
  int c = t % C;
  int p = (t / C) % Vout;
  int b = t / (C * Vout);
  int sv = sel[p];
  const int* ir = nidx + ((size_t)b * Vin + sv) * NEI;
  float m = -INFINITY;
  for (int n = 0; n < NEI; ++n)
    m = fmaxf(m, fm[((size_t)b * Vin + ir[n]) * C + c]);
  outp[((size_t)b * Vout + p) * C + c] = m;
}

__global__ void k_sel_verts(const float* __restrict__ vin, const int* __restrict__ sel,
                            float* __restrict__ vout, int Vin, int Vout) {
  int t = blockIdx.x * blockDim.x + threadIdx.x;
  int total = 4 * Vout * 3;
  if (t >= total) return;
  int d = t % 3;
  int p = (t / 3) % Vout;
  int b = t / (3 * Vout);
  vout[((size_t)b * Vout + p) * 3 + d] = vin[((size_t)b * Vin + sel[p]) * 3 + d];
}

// ===================== launch =====================
extern "C" void kernel_launch(void* const* d_in, const int* in_sizes, int n_in,
                              void* d_out, int out_size, void* d_ws, size_t ws_size,
                              hipStream_t stream) {
  (void)in_sizes; (void)n_in; (void)out_size; (void)ws_size;
  const int B = 4, V1 = 4096, V2 = 1024, V3 = 256;

  const float* vin   = (const float*)d_in[0];
  const float* dirs0 = (const float*)d_in[1];
  const float* W1 = (const float*)d_in[2];
  const float* b1 = (const float*)d_in[3];
  const float* D1 = (const float*)d_in[4];
  const float* W2 = (const float*)d_in[5];
  const float* b2 = (const float*)d_in[6];
  const float* D2 = (const float*)d_in[7];
  const float* W3 = (const float*)d_in[8];
  const float* b3 = (const float*)d_in[9];
  const float* D3 = (const float*)d_in[10];
  const float* W4 = (const float*)d_in[11];
  const float* b4 = (const float*)d_in[12];
  const float* D4 = (const float*)d_in[13];
  float* out = (float*)d_out;

  char* ws = (char*)d_ws;
  size_t off = 0;
  auto alloc = [&](size_t bytes) -> char* {
    char* p = ws + off;
    off = (off + bytes + 255) & ~(size_t)255;
    return p;
  };
  int* sel1 = (int*)alloc((size_t)V2 * 4);
  int* sel2 = (int*)alloc((size_t)V3 * 4);
  float* verts1 = (float*)alloc((size_t)B * V1 * 3 * 4);
  float* verts2 = (float*)alloc((size_t)B * V2 * 3 * 4);
  float* verts3 = (float*)alloc((size_t)B * V3 * 3 * 4);
  int* idx1 = (int*)alloc((size_t)B * V1 * NEI * 4);
  int* idx2 = (int*)alloc((size_t)B * V2 * NEI * 4);
  int* idx3 = (int*)alloc((size_t)B * V3 * NEI * 4);
  float* sd0 = (float*)alloc(3 * 128 * 4);
  float* sd1 = (float*)alloc(3 * 256 * 4);
  float* sd2 = (float*)alloc(3 * 512 * 4);
  float* sd3 = (float*)alloc(3 * 1024 * 4);
  float* sd4 = (float*)alloc(3 * 4096 * 4);
  float* bufA = (float*)alloc((size_t)B * V1 * 32 * 4);
  float* bufB = (float*)alloc((size_t)B * V1 * 64 * 4);
  float* bufC = (float*)alloc((size_t)B * V2 * 64 * 4);
  float* fbuf = (float*)alloc((size_t)B * V1 * 320 * 4);
  float* fm0 = bufA, *fm2 = bufA;
  float* fm1 = bufB, *fm3 = bufB;
  float* fm1p = bufC, *fm3p = bufC;

  static int perm1[4096];
  static int perm2[1024];
  static int selh[1280];
  jax_permutation(42u, 4096, 2, perm1);
  jax_permutation(43u, 1024, 1, perm2);
  memcpy(selh, perm1, 1024 * sizeof(int));
  memcpy(selh + 1024, perm2, 256 * sizeof(int));
  hipMemcpyAsync(sel1, selh, 1024 * sizeof(int), hipMemcpyHostToDevice, stream);
  hipMemcpyAsync(sel2, selh + 1024, 256 * sizeof(int), hipMemcpyHostToDevice, stream);

  {
    int n = B * V1 * 3;
    k_san_copy<<<(n + 255) / 256, 256, 0, stream>>>(vin, verts1, n);
  }
  k_norm_dirs<<<1, 128, 0, stream>>>(dirs0, sd0, 128);
  k_norm_dirs<<<1, 256, 0, stream>>>(D1, sd1, 256);
  k_norm_dirs<<<2, 256, 0, stream>>>(D2, sd2, 512);
  k_norm_dirs<<<4, 256, 0, stream>>>(D3, sd3, 1024);
  k_norm_dirs<<<16, 256, 0, stream>>>(D4, sd4, 4096);
  // knn level 1 (CAND = 4096/256 = 16)
  k_knn2<16><<<B * V1, 256, 0, stream>>>(verts1, idx1, V1);
  k_conv_surface<<<B * V1, 128, 0, stream>>>(verts1, idx1, sd0, fm0, V1);
  // layer1
  k_gemm_bias<<<dim3(5, 256), 256, 0, stream>>>(fm0, W1, b1, fbuf, B * V1, 320, 32);
  k_conv_layer<<<B * V1, 256, (4 * 64 + 80) * 4, stream>>>(fbuf, verts1, idx1, sd1, fm1, nullptr, V1, 64, 1, 0);
  // pool1
  {
    int total = B * V2 * 64;
    k_pool<<<(total + 255) / 256, 256, 0, stream>>>(fm1, idx1, sel1, fm1p, V1, V2, 64);
    int tv = B * V2 * 3;
    k_sel_verts<<<(tv + 255) / 256, 256, 0, stream>>>(verts1, sel1, verts2, V1, V2);
  }
  // knn level 2 (CAND = 1024/256 = 4)
  k_knn2<4><<<B * V2, 256, 0, stream>>>(verts2, idx2, V2);
  // layer2
  k_gemm_bias<<<dim3(10, 64), 256, 0, stream>>>(fm1p, W2, b2, fbuf, B * V2, 640, 64);
  k_conv_layer<<<B * V2, 256, (4 * 128 + 80) * 4, stream>>>(fbuf, verts2, idx2, sd2, fm2, nullptr, V2, 128, 1, 0);
  // layer3
  k_gemm_bias<<<dim3(20, 64), 256, 0, stream>>>(fm2, W3, b3, fbuf, B * V2, 1280, 128);
  k_conv_layer<<<B * V2, 256, (4 * 256 + 80) * 4, stream>>>(fbuf, verts2, idx2, sd3, fm3, nullptr, V2, 256, 1, 0);
  // pool2
  {
    int total = B * V3 * 256;
    k_pool<<<(total + 255) / 256, 256, 0, stream>>>(fm3, idx2, sel2, fm3p, V2, V3, 256);
    int tv = B * V3 * 3;
    k_sel_verts<<<(tv + 255) / 256, 256, 0, stream>>>(verts2, sel2, verts3, V2, V3);
  }
  // knn level 3 (CAND = 256/256 = 1)
  k_knn2<1><<<B * V3, 256, 0, stream>>>(verts3, idx3, V3);
  // layer4 -> transposed write into d_out
  k_gemm_bias<<<dim3(80, 16), 256, 0, stream>>>(fm3p, W4, b4, fbuf, B * V3, 5120, 256);
  k_conv_layer<<<B * V3, 256, (4 * 1024 + 80) * 4, stream>>>(fbuf, verts3, idx3, sd4, nullptr, out, V3, 1024, 0, 1);
}

// Round 4
// 674.281 us; speedup vs baseline: 1.5781x; 1.0758x over previous
//
#include <hip/hip_runtime.h>
#include <vector>
#include <algorithm>
#include <cstdint>
#include <cstring>
#include <cmath>

// ===================== host-side JAX threefry replication =====================
static inline uint32_t tf_rotl(uint32_t x, int r) { return (x << r) | (x >> (32 - r)); }

static void tf2x32(uint32_t k0, uint32_t k1, uint32_t x0, uint32_t x1,
                   uint32_t* o0, uint32_t* o1) {
  uint32_t ks2 = k0 ^ k1 ^ 0x1BD11BDAu;
  uint32_t v0 = x0 + k0, v1 = x1 + k1;
  static const int R0[4] = {13, 15, 26, 6}, R1[4] = {17, 29, 16, 24};
#define RND4(R) do { for (int i_ = 0; i_ < 4; ++i_) { v0 += v1; v1 = tf_rotl(v1, R[i_]); v1 ^= v0; } } while (0)
  RND4(R0); v0 += k1;  v1 += ks2 + 1u;
  RND4(R1); v0 += ks2; v1 += k0 + 2u;
  RND4(R0); v0 += k0;  v1 += k1 + 3u;
  RND4(R1); v0 += k1;  v1 += ks2 + 4u;
  RND4(R0); v0 += ks2; v1 += k0 + 5u;
#undef RND4
  *o0 = v0; *o1 = v1;
}

static void jax_permutation(uint32_t seed, int n, int rounds, int* x) {
  uint32_t k0 = 0u, k1 = seed;
  for (int i = 0; i < n; ++i) x[i] = i;
  std::vector<uint32_t> bits(n);
  std::vector<int> ord(n), xn(n);
  for (int r = 0; r < rounds; ++r) {
    uint32_t nk0, nk1, sk0, sk1;
    tf2x32(k0, k1, 0u, 0u, &nk0, &nk1);
    tf2x32(k0, k1, 0u, 1u, &sk0, &sk1);
    for (int i = 0; i < n; ++i) {
      uint32_t h, l;
      tf2x32(sk0, sk1, 0u, (uint32_t)i, &h, &l);
      bits[i] = h ^ l;
    }
    for (int i = 0; i < n; ++i) ord[i] = i;
    std::stable_sort(ord.begin(), ord.end(),
                     [&](int a, int b) { return bits[a] < bits[b]; });
    for (int i = 0; i < n; ++i) xn[i] = x[ord[i]];
    memcpy(x, xn.data(), (size_t)n * sizeof(int));
    k0 = nk0; k1 = nk1;
  }
}

// ===================== device kernels =====================
#define NEI 20

__device__ __forceinline__ float san(float v) {
  v = (v != v) ? 0.0f : v;
  return fmaxf(-1e4f, fminf(v, 1e4f));
}

__global__ void k_san_copy(const float* __restrict__ in, float* __restrict__ out, int n) {
  int i = blockIdx.x * blockDim.x + threadIdx.x;
  if (i < n) out[i] = san(in[i]);
}

__global__ void k_norm_dirs(const float* __restrict__ d, float* __restrict__ sd, int E) {
  int e = blockIdx.x * blockDim.x + threadIdx.x;
  if (e >= E) return;
  float a = san(d[e]);
  float b = san(d[E + e]);
  float c = san(d[2 * E + e]);
  float nrm = sqrtf(a * a + b * b + c * c);
  float m = fmaxf(nrm, 1e-12f);
  sd[e] = a / m; sd[E + e] = b / m; sd[2 * E + e] = c / m;
}

// KNN v3 (lazy rescan): one block (256 thr) per query row. CAND keys/thread in
// registers; per-thread running local-min m_loc. Per round: block-min reduce of
// m_loc only; ONLY the winning thread (exec-masked branch -> 3 of 4 waves skip)
// re-scans its keys to recompute m_loc with filter > bm. Keys unique
// (ordered_float(dist)<<32 | j) => exact lax.top_k tie semantics preserved.
template <int CAND>
__global__ __launch_bounds__(256) void k_knn3(const float* __restrict__ verts,
                                              int* __restrict__ nidx, int V) {
  int row = blockIdx.x;
  int b = row / V, i = row % V;
  const float* vb = verts + (size_t)b * V * 3;
  __shared__ unsigned long long red[2][4];
  int tid = threadIdx.x;
  float xi = vb[3 * i], yi = vb[3 * i + 1], zi = vb[3 * i + 2];
  float sqi = xi * xi + yi * yi + zi * zi;
  unsigned long long key[CAND];
#pragma unroll
  for (int c = 0; c < CAND; ++c) {
    int j = c * 256 + tid;
    float xj = vb[3 * j], yj = vb[3 * j + 1], zj = vb[3 * j + 2];
    float sqj = xj * xj + yj * yj + zj * zj;
    float dot = xi * xj + yi * yj + zi * zj;
    float dd = (sqi + sqj) - 2.0f * dot;
    unsigned u = __float_as_uint(dd);
    u ^= (u & 0x80000000u) ? 0xFFFFFFFFu : 0x80000000u;  // total-order map
    key[c] = (((unsigned long long)u) << 32) | (unsigned)j;
  }
  // initial per-thread local min
  unsigned long long m_loc = key[0];
#pragma unroll
  for (int c = 1; c < CAND; ++c)
    if (key[c] < m_loc) m_loc = key[c];

  for (int r = 0; r < 21; ++r) {
    unsigned long long m = m_loc;
    for (int o = 32; o > 0; o >>= 1) {
      unsigned long long t = __shfl_down(m, o);
      if (t < m) m = t;
    }
    if ((tid & 63) == 0) red[r & 1][tid >> 6] = m;
    __syncthreads();
    unsigned long long bm = red[r & 1][0];
#pragma unroll
    for (int w = 1; w < 4; ++w) {
      unsigned long long t = red[r & 1][w];
      if (t < bm) bm = t;
    }
    if (r > 0 && tid == 0) nidx[(size_t)row * NEI + (r - 1)] = (int)(bm & 0xFFFFFFFFu);
    // lazy rescan: only the winning thread recomputes its local min
    if (m_loc == bm) {
      unsigned long long nm = ~0ULL;
#pragma unroll
      for (int c = 0; c < CAND; ++c)
        if (key[c] > bm && key[c] < nm) nm = key[c];
      m_loc = nm;
    }
  }
}

// conv_surface: C=32, E=128. One block (128 thr) per (b,v).
__global__ __launch_bounds__(128) void k_conv_surface(const float* __restrict__ verts,
                                                      const int* __restrict__ nidx,
                                                      const float* __restrict__ sd,
                                                      float* __restrict__ fm, int V) {
  int row = blockIdx.x;
  int b = row / V, v = row % V;
  const float* vb = verts + (size_t)b * V * 3;
  __shared__ float nd[60];
  __shared__ float mcol[128];
  int tid = threadIdx.x;
  if (tid < NEI) {
    int j = nidx[(size_t)row * NEI + tid];
    float dx = vb[3 * j] - vb[3 * v];
    float dy = vb[3 * j + 1] - vb[3 * v + 1];
    float dz = vb[3 * j + 2] - vb[3 * v + 2];
    float nrm = sqrtf(dx * dx + dy * dy + dz * dz);
    float m = fmaxf(nrm, 1e-12f);
    nd[tid * 3] = dx / m; nd[tid * 3 + 1] = dy / m; nd[tid * 3 + 2] = dz / m;
  }
  __syncthreads();
  {
    int e = tid;
    float s0 = sd[e], s1 = sd[128 + e], s2 = sd[256 + e];
    float me = 0.0f;
#pragma unroll
    for (int n = 0; n < NEI; ++n) {
      float th = nd[3 * n] * s0 + nd[3 * n + 1] * s1 + nd[3 * n + 2] * s2;
      th = fmaxf(th, 0.0f);
      me = fmaxf(me, th);
    }
    mcol[e] = me;
  }
  __syncthreads();
  if (tid < 32) {
    float o = mcol[tid] + mcol[32 + tid] + mcol[64 + tid] + mcol[96 + tid];
    o = fmaxf(o, 0.0f);
    fm[(size_t)row * 32 + tid] = o;
  }
}

// fp32 tiled GEMM: C[M,N] = A[M,K] * W[K,N] + bias[N]
__global__ __launch_bounds__(256) void k_gemm_bias(const float* __restrict__ A,
                                                   const float* __restrict__ W,
                                                   const float* __restrict__ bias,
                                                   float* __restrict__ Cm,
                                                   int M, int N, int K) {
  __shared__ float As[16][65];
  __shared__ float Bs[16][65];
  int n0 = blockIdx.x * 64, m0 = blockIdx.y * 64;
  int tx = threadIdx.x & 15, ty = threadIdx.x >> 4;
  float acc[4][4] = {};
  for (int k0 = 0; k0 < K; k0 += 16) {
    for (int t = threadIdx.x; t < 1024; t += 256) {
      int mm = t >> 4, kk = t & 15;
      int m = m0 + mm;
      As[kk][mm] = (m < M) ? A[(size_t)m * K + (k0 + kk)] : 0.0f;
    }
    for (int t = threadIdx.x; t < 1024; t += 256) {
      int kk = t >> 6, nn = t & 63;
      int n = n0 + nn;
      Bs[kk][nn] = (n < N) ? san(W[(size_t)(k0 + kk) * N + n]) : 0.0f;
    }
    __syncthreads();
#pragma unroll
    for (int kk = 0; kk < 16; ++kk) {
      float a[4], bb[4];
#pragma unroll
      for (int i = 0; i < 4; ++i) { a[i] = As[kk][(ty << 2) + i]; bb[i] = Bs[kk][(tx << 2) + i]; }
#pragma unroll
      for (int i = 0; i < 4; ++i)
#pragma unroll
        for (int j = 0; j < 4; ++j) acc[i][j] += a[i] * bb[j];
    }
    __syncthreads();
  }
  for (int i = 0; i < 4; ++i)
    for (int j = 0; j < 4; ++j) {
      int m = m0 + (ty << 2) + i, n = n0 + (tx << 2) + j;
      if (m < M && n < N) Cm[(size_t)m * N + n] = acc[i][j] + san(bias[n]);
    }
}

// conv layer: out[c] = f[row][c] + sum_s max_n relu(nd_n . sd_e) * f[j_n][C+e], e=s*C+c
__global__ __launch_bounds__(256) void k_conv_layer(const float* __restrict__ f,
                                                    const float* __restrict__ verts,
                                                    const int* __restrict__ nidx,
                                                    const float* __restrict__ sd,
                                                    float* __restrict__ outf,
                                                    float* __restrict__ outt,
                                                    int V, int C, int relu_out, int transpose_out) {
  int row = blockIdx.x;
  int b = row / V, v = row % V;
  int E = 4 * C;
  extern __shared__ float sm[];
  float* mcol = sm;           // E floats
  float* nd = sm + E;         // 60 floats
  int* jr = (int*)(nd + 60);  // 20 ints
  int tid = threadIdx.x;
  const float* vb = verts + (size_t)b * V * 3;
  if (tid < NEI) {
    int j = nidx[(size_t)row * NEI + tid];
    jr[tid] = j;
    float dx = vb[3 * j] - vb[3 * v];
    float dy = vb[3 * j + 1] - vb[3 * v + 1];
    float dz = vb[3 * j + 2] - vb[3 * v + 2];
    float nrm = sqrtf(dx * dx + dy * dy + dz * dz);
    float m = fmaxf(nrm, 1e-12f);
    nd[tid * 3] = dx / m; nd[tid * 3 + 1] = dy / m; nd[tid * 3 + 2] = dz / m;
  }
  __syncthreads();
  size_t fb = (size_t)b * V;
  int fivec = 5 * C;
  for (int e = tid; e < E; e += blockDim.x) {
    float s0 = sd[e], s1 = sd[E + e], s2 = sd[2 * E + e];
    float me = -INFINITY;
#pragma unroll
    for (int n = 0; n < NEI; ++n) {
      float th = nd[3 * n] * s0 + nd[3 * n + 1] * s1 + nd[3 * n + 2] * s2;
      th = fmaxf(th, 0.0f);
      float fv = f[(fb + jr[n]) * (size_t)fivec + C + e];
      me = fmaxf(me, th * fv);
    }
    mcol[e] = me;
  }
  __syncthreads();
  for (int c = tid; c < C; c += blockDim.x) {
    float o = f[(size_t)row * fivec + c] + mcol[c] + mcol[C + c] + mcol[2 * C + c] + mcol[3 * C + c];
    if (relu_out) o = fmaxf(o, 0.0f);
    if (transpose_out) outt[((size_t)b * C + c) * V + v] = o;
    else outf[(size_t)row * C + c] = o;
  }
}

__global__ void k_pool(const float* __restrict__ fm, const int* __restrict__ nidx,
                       const int* __restrict__ sel, float* __restrict__ outp,
                       int Vin, int Vout, int C) {
  int t = blockIdx.x * blockDim.x + threadIdx.x;
  int total = 4 * Vout * C;
  if (t >= total) return;
  int c = t % C;
  int p = (t / C) % Vout;
  int b = t / (C * Vout);
  int sv = sel[p];
  const int* ir = nidx + ((size_t)b * Vin + sv) * NEI;
  float m = -INFINITY;
#pragma unroll
  for (int n = 0; n < NEI; ++n)
    m = fmaxf(m, fm[((size_t)b * Vin + ir[n]) * C + c]);
  outp[((size_t)b * Vout + p) * C + c] = m;
}

__global__ void k_sel_verts(const float* __restrict__ vin, const int* __restrict__ sel,
                            float* __restrict__ vout, int Vin, int Vout) {
  int t = blockIdx.x * blockDim.x + threadIdx.x;
  int total = 4 * Vout * 3;
  if (t >= total) return;
  int d = t % 3;
  int p = (t / 3) % Vout;
  int b = t / (3 * Vout);
  vout[((size_t)b * Vout + p) * 3 + d] = vin[((size_t)b * Vin + sel[p]) * 3 + d];
}

// ===================== launch =====================
extern "C" void kernel_launch(void* const* d_in, const int* in_sizes, int n_in,
                              void* d_out, int out_size, void* d_ws, size_t ws_size,
                              hipStream_t stream) {
  (void)in_sizes; (void)n_in; (void)out_size; (void)ws_size;
  const int B = 4, V1 = 4096, V2 = 1024, V3 = 256;

  const float* vin   = (const float*)d_in[0];
  const float* dirs0 = (const float*)d_in[1];
  const float* W1 = (const float*)d_in[2];
  const float* b1 = (const float*)d_in[3];
  const float* D1 = (const float*)d_in[4];
  const float* W2 = (const float*)d_in[5];
  const float* b2 = (const float*)d_in[6];
  const float* D2 = (const float*)d_in[7];
  const float* W3 = (const float*)d_in[8];
  const float* b3 = (const float*)d_in[9];
  const float* D3 = (const float*)d_in[10];
  const float* W4 = (const float*)d_in[11];
  const float* b4 = (const float*)d_in[12];
  const float* D4 = (const float*)d_in[13];
  float* out = (float*)d_out;

  char* ws = (char*)d_ws;
  size_t off = 0;
  auto alloc = [&](size_t bytes) -> char* {
    char* p = ws + off;
    off = (off + bytes + 255) & ~(size_t)255;
    return p;
  };
  int* sel1 = (int*)alloc((size_t)V2 * 4);
  int* sel2 = (int*)alloc((size_t)V3 * 4);
  float* verts1 = (float*)alloc((size_t)B * V1 * 3 * 4);
  float* verts2 = (float*)alloc((size_t)B * V2 * 3 * 4);
  float* verts3 = (float*)alloc((size_t)B * V3 * 3 * 4);
  int* idx1 = (int*)alloc((size_t)B * V1 * NEI * 4);
  int* idx2 = (int*)alloc((size_t)B * V2 * NEI * 4);
  int* idx3 = (int*)alloc((size_t)B * V3 * NEI * 4);
  float* sd0 = (float*)alloc(3 * 128 * 4);
  float* sd1 = (float*)alloc(3 * 256 * 4);
  float* sd2 = (float*)alloc(3 * 512 * 4);
  float* sd3 = (float*)alloc(3 * 1024 * 4);
  float* sd4 = (float*)alloc(3 * 4096 * 4);
  float* bufA = (float*)alloc((size_t)B * V1 * 32 * 4);
  float* bufB = (float*)alloc((size_t)B * V1 * 64 * 4);
  float* bufC = (float*)alloc((size_t)B * V2 * 64 * 4);
  float* fbuf = (float*)alloc((size_t)B * V1 * 320 * 4);
  float* fm0 = bufA, *fm2 = bufA;
  float* fm1 = bufB, *fm3 = bufB;
  float* fm1p = bufC, *fm3p = bufC;

  static int perm1[4096];
  static int perm2[1024];
  static int selh[1280];
  jax_permutation(42u, 4096, 2, perm1);
  jax_permutation(43u, 1024, 1, perm2);
  memcpy(selh, perm1, 1024 * sizeof(int));
  memcpy(selh + 1024, perm2, 256 * sizeof(int));
  hipMemcpyAsync(sel1, selh, 1024 * sizeof(int), hipMemcpyHostToDevice, stream);
  hipMemcpyAsync(sel2, selh + 1024, 256 * sizeof(int), hipMemcpyHostToDevice, stream);

  {
    int n = B * V1 * 3;
    k_san_copy<<<(n + 255) / 256, 256, 0, stream>>>(vin, verts1, n);
  }
  k_norm_dirs<<<1, 128, 0, stream>>>(dirs0, sd0, 128);
  k_norm_dirs<<<1, 256, 0, stream>>>(D1, sd1, 256);
  k_norm_dirs<<<2, 256, 0, stream>>>(D2, sd2, 512);
  k_norm_dirs<<<4, 256, 0, stream>>>(D3, sd3, 1024);
  k_norm_dirs<<<16, 256, 0, stream>>>(D4, sd4, 4096);
  // knn level 1 (CAND = 16)
  k_knn3<16><<<B * V1, 256, 0, stream>>>(verts1, idx1, V1);
  k_conv_surface<<<B * V1, 128, 0, stream>>>(verts1, idx1, sd0, fm0, V1);
  // layer1
  k_gemm_bias<<<dim3(5, 256), 256, 0, stream>>>(fm0, W1, b1, fbuf, B * V1, 320, 32);
  k_conv_layer<<<B * V1, 256, (4 * 64 + 80) * 4, stream>>>(fbuf, verts1, idx1, sd1, fm1, nullptr, V1, 64, 1, 0);
  // pool1
  {
    int total = B * V2 * 64;
    k_pool<<<(total + 255) / 256, 256, 0, stream>>>(fm1, idx1, sel1, fm1p, V1, V2, 64);
    int tv = B * V2 * 3;
    k_sel_verts<<<(tv + 255) / 256, 256, 0, stream>>>(verts1, sel1, verts2, V1, V2);
  }
  // knn level 2 (CAND = 4)
  k_knn3<4><<<B * V2, 256, 0, stream>>>(verts2, idx2, V2);
  // layer2
  k_gemm_bias<<<dim3(10, 64), 256, 0, stream>>>(fm1p, W2, b2, fbuf, B * V2, 640, 64);
  k_conv_layer<<<B * V2, 256, (4 * 128 + 80) * 4, stream>>>(fbuf, verts2, idx2, sd2, fm2, nullptr, V2, 128, 1, 0);
  // layer3
  k_gemm_bias<<<dim3(20, 64), 256, 0, stream>>>(fm2, W3, b3, fbuf, B * V2, 1280, 128);
  k_conv_layer<<<B * V2, 256, (4 * 256 + 80) * 4, stream>>>(fbuf, verts2, idx2, sd3, fm3, nullptr, V2, 256, 1, 0);
  // pool2
  {
    int total = B * V3 * 256;
    k_pool<<<(total + 255) / 256, 256, 0, stream>>>(fm3, idx2, sel2, fm3p, V2, V3, 256);
    int tv = B * V3 * 3;
    k_sel_verts<<<(tv + 255) / 256, 256, 0, stream>>>(verts2, sel2, verts3, V2, V3);
  }
  // knn level 3 (CAND = 1)
  k_knn3<1><<<B * V3, 256, 0, stream>>>(verts3, idx3, V3);
  // layer4 -> transposed write into d_out
  k_gemm_bias<<<dim3(80, 16), 256, 0, stream>>>(fm3p, W4, b4, fbuf, B * V3, 5120, 256);
  k_conv_layer<<<B * V3, 256, (4 * 1024 + 80) * 4, stream>>>(fbuf, verts3, idx3, sd4, nullptr, out, V3, 1024, 0, 1);
}

// Round 5
// 528.455 us; speedup vs baseline: 2.0136x; 1.2759x over previous
//
#include <hip/hip_runtime.h>
#include <vector>
#include <algorithm>
#include <cstdint>
#include <cstring>
#include <cmath>

// ===================== host-side JAX threefry replication =====================
static inline uint32_t tf_rotl(uint32_t x, int r) { return (x << r) | (x >> (32 - r)); }

static void tf2x32(uint32_t k0, uint32_t k1, uint32_t x0, uint32_t x1,
                   uint32_t* o0, uint32_t* o1) {
  uint32_t ks2 = k0 ^ k1 ^ 0x1BD11BDAu;
  uint32_t v0 = x0 + k0, v1 = x1 + k1;
  static const int R0[4] = {13, 15, 26, 6}, R1[4] = {17, 29, 16, 24};
#define RND4(R) do { for (int i_ = 0; i_ < 4; ++i_) { v0 += v1; v1 = tf_rotl(v1, R[i_]); v1 ^= v0; } } while (0)
  RND4(R0); v0 += k1;  v1 += ks2 + 1u;
  RND4(R1); v0 += ks2; v1 += k0 + 2u;
  RND4(R0); v0 += k0;  v1 += k1 + 3u;
  RND4(R1); v0 += k1;  v1 += ks2 + 4u;
  RND4(R0); v0 += ks2; v1 += k0 + 5u;
#undef RND4
  *o0 = v0; *o1 = v1;
}

static void jax_permutation(uint32_t seed, int n, int rounds, int* x) {
  uint32_t k0 = 0u, k1 = seed;
  for (int i = 0; i < n; ++i) x[i] = i;
  std::vector<uint32_t> bits(n);
  std::vector<int> ord(n), xn(n);
  for (int r = 0; r < rounds; ++r) {
    uint32_t nk0, nk1, sk0, sk1;
    tf2x32(k0, k1, 0u, 0u, &nk0, &nk1);
    tf2x32(k0, k1, 0u, 1u, &sk0, &sk1);
    for (int i = 0; i < n; ++i) {
      uint32_t h, l;
      tf2x32(sk0, sk1, 0u, (uint32_t)i, &h, &l);
      bits[i] = h ^ l;
    }
    for (int i = 0; i < n; ++i) ord[i] = i;
    std::stable_sort(ord.begin(), ord.end(),
                     [&](int a, int b) { return bits[a] < bits[b]; });
    for (int i = 0; i < n; ++i) xn[i] = x[ord[i]];
    memcpy(x, xn.data(), (size_t)n * sizeof(int));
    k0 = nk0; k1 = nk1;
  }
}

// ===================== device kernels =====================
#define NEI 20

__device__ __forceinline__ float san(float v) {
  v = (v != v) ? 0.0f : v;
  return fmaxf(-1e4f, fminf(v, 1e4f));
}

__global__ void k_san_copy(const float* __restrict__ in, float* __restrict__ out, int n) {
  int i = blockIdx.x * blockDim.x + threadIdx.x;
  if (i < n) out[i] = san(in[i]);
}

__global__ void k_norm_dirs(const float* __restrict__ d, float* __restrict__ sd, int E) {
  int e = blockIdx.x * blockDim.x + threadIdx.x;
  if (e >= E) return;
  float a = san(d[e]);
  float b = san(d[E + e]);
  float c = san(d[2 * E + e]);
  float nrm = sqrtf(a * a + b * b + c * c);
  float m = fmaxf(nrm, 1e-12f);
  sd[e] = a / m; sd[E + e] = b / m; sd[2 * E + e] = c / m;
}

// KNN v4: one WAVE per query (4 queries/block, no barriers, no LDS).
// Each lane streams V/64 candidates keeping a sorted top-3 queue in registers;
// 21 rounds of 6-step shfl_xor butterfly over queue heads; winner lane pops and
// stores. Exec-masked full rescan refill when a lane's queue empties (rare, exact).
// Keys (ordered_float(dist)<<32 | j) unique => exact lax.top_k tie semantics.
template <int VCAND>
__global__ __launch_bounds__(256) void k_knn4(const float* __restrict__ verts,
                                              int* __restrict__ nidx, int V) {
  const int wid = threadIdx.x >> 6;
  const int lane = threadIdx.x & 63;
  const int row = blockIdx.x * 4 + wid;
  const int b = row / V, i = row % V;
  const float* vb = verts + (size_t)b * V * 3;
  const float xi = vb[3 * i], yi = vb[3 * i + 1], zi = vb[3 * i + 2];
  const float sqi = xi * xi + yi * yi + zi * zi;

  unsigned long long q0 = ~0ULL, q1 = ~0ULL, q2 = ~0ULL;
#pragma unroll 8
  for (int c = 0; c < VCAND; ++c) {
    int j = c * 64 + lane;
    float xj = vb[3 * j], yj = vb[3 * j + 1], zj = vb[3 * j + 2];
    float sqj = xj * xj + yj * yj + zj * zj;
    float dot = xi * xj + yi * yj + zi * zj;
    float dd = (sqi + sqj) - 2.0f * dot;
    unsigned u = __float_as_uint(dd);
    u ^= (u & 0x80000000u) ? 0xFFFFFFFFu : 0x80000000u;  // total-order map
    unsigned long long k = (((unsigned long long)u) << 32) | (unsigned)j;
    if (k < q2) {
      if (k < q1) {
        q2 = q1;
        if (k < q0) { q1 = q0; q0 = k; } else { q1 = k; }
      } else {
        q2 = k;
      }
    }
  }

  for (int r = 0; r < 21; ++r) {
    unsigned long long m = q0;
#pragma unroll
    for (int o = 1; o < 64; o <<= 1) {
      unsigned long long t = __shfl_xor(m, o);
      if (t < m) m = t;
    }
    if (q0 == m) {
      // this lane owns the global minimum
      if (r > 0) nidx[(size_t)row * NEI + (r - 1)] = (int)(m & 0xFFFFFFFFu);
      q0 = q1; q1 = q2; q2 = ~0ULL;
      if (q0 == ~0ULL) {
        // refill (rare): recompute keys, find min key > m
        unsigned long long nm = ~0ULL;
        for (int c = 0; c < VCAND; ++c) {
          int j = c * 64 + lane;
          float xj = vb[3 * j], yj = vb[3 * j + 1], zj = vb[3 * j + 2];
          float sqj = xj * xj + yj * yj + zj * zj;
          float dot = xi * xj + yi * yj + zi * zj;
          float dd = (sqi + sqj) - 2.0f * dot;
          unsigned u = __float_as_uint(dd);
          u ^= (u & 0x80000000u) ? 0xFFFFFFFFu : 0x80000000u;
          unsigned long long k = (((unsigned long long)u) << 32) | (unsigned)j;
          if (k > m && k < nm) nm = k;
        }
        q0 = nm;
      }
    }
  }
}

// conv_surface: C=32, E=128. One block (128 thr) per (b,v).
__global__ __launch_bounds__(128) void k_conv_surface(const float* __restrict__ verts,
                                                      const int* __restrict__ nidx,
                                                      const float* __restrict__ sd,
                                                      float* __restrict__ fm, int V) {
  int row = blockIdx.x;
  int b = row / V, v = row % V;
  const float* vb = verts + (size_t)b * V * 3;
  __shared__ float nd[60];
  __shared__ float mcol[128];
  int tid = threadIdx.x;
  if (tid < NEI) {
    int j = nidx[(size_t)row * NEI + tid];
    float dx = vb[3 * j] - vb[3 * v];
    float dy = vb[3 * j + 1] - vb[3 * v + 1];
    float dz = vb[3 * j + 2] - vb[3 * v + 2];
    float nrm = sqrtf(dx * dx + dy * dy + dz * dz);
    float m = fmaxf(nrm, 1e-12f);
    nd[tid * 3] = dx / m; nd[tid * 3 + 1] = dy / m; nd[tid * 3 + 2] = dz / m;
  }
  __syncthreads();
  {
    int e = tid;
    float s0 = sd[e], s1 = sd[128 + e], s2 = sd[256 + e];
    float me = 0.0f;
#pragma unroll
    for (int n = 0; n < NEI; ++n) {
      float th = nd[3 * n] * s0 + nd[3 * n + 1] * s1 + nd[3 * n + 2] * s2;
      th = fmaxf(th, 0.0f);
      me = fmaxf(me, th);
    }
    mcol[e] = me;
  }
  __syncthreads();
  if (tid < 32) {
    float o = mcol[tid] + mcol[32 + tid] + mcol[64 + tid] + mcol[96 + tid];
    o = fmaxf(o, 0.0f);
    fm[(size_t)row * 32 + tid] = o;
  }
}

// fp32 tiled GEMM: C[M,N] = A[M,K] * W[K,N] + bias[N]
__global__ __launch_bounds__(256) void k_gemm_bias(const float* __restrict__ A,
                                                   const float* __restrict__ W,
                                                   const float* __restrict__ bias,
                                                   float* __restrict__ Cm,
                                                   int M, int N, int K) {
  __shared__ float As[16][65];
  __shared__ float Bs[16][65];
  int n0 = blockIdx.x * 64, m0 = blockIdx.y * 64;
  int tx = threadIdx.x & 15, ty = threadIdx.x >> 4;
  float acc[4][4] = {};
  for (int k0 = 0; k0 < K; k0 += 16) {
    for (int t = threadIdx.x; t < 1024; t += 256) {
      int mm = t >> 4, kk = t & 15;
      int m = m0 + mm;
      As[kk][mm] = (m < M) ? A[(size_t)m * K + (k0 + kk)] : 0.0f;
    }
    for (int t = threadIdx.x; t < 1024; t += 256) {
      int kk = t >> 6, nn = t & 63;
      int n = n0 + nn;
      Bs[kk][nn] = (n < N) ? san(W[(size_t)(k0 + kk) * N + n]) : 0.0f;
    }
    __syncthreads();
#pragma unroll
    for (int kk = 0; kk < 16; ++kk) {
      float a[4], bb[4];
#pragma unroll
      for (int i = 0; i < 4; ++i) { a[i] = As[kk][(ty << 2) + i]; bb[i] = Bs[kk][(tx << 2) + i]; }
#pragma unroll
      for (int i = 0; i < 4; ++i)
#pragma unroll
        for (int j = 0; j < 4; ++j) acc[i][j] += a[i] * bb[j];
    }
    __syncthreads();
  }
  for (int i = 0; i < 4; ++i)
    for (int j = 0; j < 4; ++j) {
      int m = m0 + (ty << 2) + i, n = n0 + (tx << 2) + j;
      if (m < M && n < N) Cm[(size_t)m * N + n] = acc[i][j] + san(bias[n]);
    }
}

// conv layer: out[c] = f[row][c] + sum_s max_n relu(nd_n . sd_e) * f[j_n][C+e], e=s*C+c
__global__ __launch_bounds__(256) void k_conv_layer(const float* __restrict__ f,
                                                    const float* __restrict__ verts,
                                                    const int* __restrict__ nidx,
                                                    const float* __restrict__ sd,
                                                    float* __restrict__ outf,
                                                    float* __restrict__ outt,
                                                    int V, int C, int relu_out, int transpose_out) {
  int row = blockIdx.x;
  int b = row / V, v = row % V;
  int E = 4 * C;
  extern __shared__ float sm[];
  float* mcol = sm;           // E floats
  float* nd = sm + E;         // 60 floats
  int* jr = (int*)(nd + 60);  // 20 ints
  int tid = threadIdx.x;
  const float* vb = verts + (size_t)b * V * 3;
  if (tid < NEI) {
    int j = nidx[(size_t)row * NEI + tid];
    jr[tid] = j;
    float dx = vb[3 * j] - vb[3 * v];
    float dy = vb[3 * j + 1] - vb[3 * v + 1];
    float dz = vb[3 * j + 2] - vb[3 * v + 2];
    float nrm = sqrtf(dx * dx + dy * dy + dz * dz);
    float m = fmaxf(nrm, 1e-12f);
    nd[tid * 3] = dx / m; nd[tid * 3 + 1] = dy / m; nd[tid * 3 + 2] = dz / m;
  }
  __syncthreads();
  size_t fb = (size_t)b * V;
  int fivec = 5 * C;
  for (int e = tid; e < E; e += blockDim.x) {
    float s0 = sd[e], s1 = sd[E + e], s2 = sd[2 * E + e];
    float me = -INFINITY;
#pragma unroll
    for (int n = 0; n < NEI; ++n) {
      float th = nd[3 * n] * s0 + nd[3 * n + 1] * s1 + nd[3 * n + 2] * s2;
      th = fmaxf(th, 0.0f);
      float fv = f[(fb + jr[n]) * (size_t)fivec + C + e];
      me = fmaxf(me, th * fv);
    }
    mcol[e] = me;
  }
  __syncthreads();
  for (int c = tid; c < C; c += blockDim.x) {
    float o = f[(size_t)row * fivec + c] + mcol[c] + mcol[C + c] + mcol[2 * C + c] + mcol[3 * C + c];
    if (relu_out) o = fmaxf(o, 0.0f);
    if (transpose_out) outt[((size_t)b * C + c) * V + v] = o;
    else outf[(size_t)row * C + c] = o;
  }
}

__global__ void k_pool(const float* __restrict__ fm, const int* __restrict__ nidx,
                       const int* __restrict__ sel, float* __restrict__ outp,
                       int Vin, int Vout, int C) {
  int t = blockIdx.x * blockDim.x + threadIdx.x;
  int total = 4 * Vout * C;
  if (t >= total) return;
  int c = t % C;
  int p = (t / C) % Vout;
  int b = t / (C * Vout);
  int sv = sel[p];
  const int* ir = nidx + ((size_t)b * Vin + sv) * NEI;
  float m = -INFINITY;
#pragma unroll
  for (int n = 0; n < NEI; ++n)
    m = fmaxf(m, fm[((size_t)b * Vin + ir[n]) * C + c]);
  outp[((size_t)b * Vout + p) * C + c] = m;
}

__global__ void k_sel_verts(const float* __restrict__ vin, const int* __restrict__ sel,
                            float* __restrict__ vout, int Vin, int Vout) {
  int t = blockIdx.x * blockDim.x + threadIdx.x;
  int total = 4 * Vout * 3;
  if (t >= total) return;
  int d = t % 3;
  int p = (t / 3) % Vout;
  int b = t / (3 * Vout);
  vout[((size_t)b * Vout + p) * 3 + d] = vin[((size_t)b * Vin + sel[p]) * 3 + d];
}

// ===================== launch =====================
extern "C" void kernel_launch(void* const* d_in, const int* in_sizes, int n_in,
                              void* d_out, int out_size, void* d_ws, size_t ws_size,
                              hipStream_t stream) {
  (void)in_sizes; (void)n_in; (void)out_size; (void)ws_size;
  const int B = 4, V1 = 4096, V2 = 1024, V3 = 256;

  const float* vin   = (const float*)d_in[0];
  const float* dirs0 = (const float*)d_in[1];
  const float* W1 = (const float*)d_in[2];
  const float* b1 = (const float*)d_in[3];
  const float* D1 = (const float*)d_in[4];
  const float* W2 = (const float*)d_in[5];
  const float* b2 = (const float*)d_in[6];
  const float* D2 = (const float*)d_in[7];
  const float* W3 = (const float*)d_in[8];
  const float* b3 = (const float*)d_in[9];
  const float* D3 = (const float*)d_in[10];
  const float* W4 = (const float*)d_in[11];
  const float* b4 = (const float*)d_in[12];
  const float* D4 = (const float*)d_in[13];
  float* out = (float*)d_out;

  char* ws = (char*)d_ws;
  size_t off = 0;
  auto alloc = [&](size_t bytes) -> char* {
    char* p = ws + off;
    off = (off + bytes + 255) & ~(size_t)255;
    return p;
  };
  int* sel1 = (int*)alloc((size_t)V2 * 4);
  int* sel2 = (int*)alloc((size_t)V3 * 4);
  float* verts1 = (float*)alloc((size_t)B * V1 * 3 * 4);
  float* verts2 = (float*)alloc((size_t)B * V2 * 3 * 4);
  float* verts3 = (float*)alloc((size_t)B * V3 * 3 * 4);
  int* idx1 = (int*)alloc((size_t)B * V1 * NEI * 4);
  int* idx2 = (int*)alloc((size_t)B * V2 * NEI * 4);
  int* idx3 = (int*)alloc((size_t)B * V3 * NEI * 4);
  float* sd0 = (float*)alloc(3 * 128 * 4);
  float* sd1 = (float*)alloc(3 * 256 * 4);
  float* sd2 = (float*)alloc(3 * 512 * 4);
  float* sd3 = (float*)alloc(3 * 1024 * 4);
  float* sd4 = (float*)alloc(3 * 4096 * 4);
  float* bufA = (float*)alloc((size_t)B * V1 * 32 * 4);
  float* bufB = (float*)alloc((size_t)B * V1 * 64 * 4);
  float* bufC = (float*)alloc((size_t)B * V2 * 64 * 4);
  float* fbuf = (float*)alloc((size_t)B * V1 * 320 * 4);
  float* fm0 = bufA, *fm2 = bufA;
  float* fm1 = bufB, *fm3 = bufB;
  float* fm1p = bufC, *fm3p = bufC;

  static int perm1[4096];
  static int perm2[1024];
  static int selh[1280];
  jax_permutation(42u, 4096, 2, perm1);
  jax_permutation(43u, 1024, 1, perm2);
  memcpy(selh, perm1, 1024 * sizeof(int));
  memcpy(selh + 1024, perm2, 256 * sizeof(int));
  hipMemcpyAsync(sel1, selh, 1024 * sizeof(int), hipMemcpyHostToDevice, stream);
  hipMemcpyAsync(sel2, selh + 1024, 256 * sizeof(int), hipMemcpyHostToDevice, stream);

  {
    int n = B * V1 * 3;
    k_san_copy<<<(n + 255) / 256, 256, 0, stream>>>(vin, verts1, n);
  }
  k_norm_dirs<<<1, 128, 0, stream>>>(dirs0, sd0, 128);
  k_norm_dirs<<<1, 256, 0, stream>>>(D1, sd1, 256);
  k_norm_dirs<<<2, 256, 0, stream>>>(D2, sd2, 512);
  k_norm_dirs<<<4, 256, 0, stream>>>(D3, sd3, 1024);
  k_norm_dirs<<<16, 256, 0, stream>>>(D4, sd4, 4096);
  // knn level 1 (VCAND = 4096/64 = 64), 4 queries per block
  k_knn4<64><<<B * V1 / 4, 256, 0, stream>>>(verts1, idx1, V1);
  k_conv_surface<<<B * V1, 128, 0, stream>>>(verts1, idx1, sd0, fm0, V1);
  // layer1
  k_gemm_bias<<<dim3(5, 256), 256, 0, stream>>>(fm0, W1, b1, fbuf, B * V1, 320, 32);
  k_conv_layer<<<B * V1, 256, (4 * 64 + 80) * 4, stream>>>(fbuf, verts1, idx1, sd1, fm1, nullptr, V1, 64, 1, 0);
  // pool1
  {
    int total = B * V2 * 64;
    k_pool<<<(total + 255) / 256, 256, 0, stream>>>(fm1, idx1, sel1, fm1p, V1, V2, 64);
    int tv = B * V2 * 3;
    k_sel_verts<<<(tv + 255) / 256, 256, 0, stream>>>(verts1, sel1, verts2, V1, V2);
  }
  // knn level 2 (VCAND = 1024/64 = 16)
  k_knn4<16><<<B * V2 / 4, 256, 0, stream>>>(verts2, idx2, V2);
  // layer2
  k_gemm_bias<<<dim3(10, 64), 256, 0, stream>>>(fm1p, W2, b2, fbuf, B * V2, 640, 64);
  k_conv_layer<<<B * V2, 256, (4 * 128 + 80) * 4, stream>>>(fbuf, verts2, idx2, sd2, fm2, nullptr, V2, 128, 1, 0);
  // layer3
  k_gemm_bias<<<dim3(20, 64), 256, 0, stream>>>(fm2, W3, b3, fbuf, B * V2, 1280, 128);
  k_conv_layer<<<B * V2, 256, (4 * 256 + 80) * 4, stream>>>(fbuf, verts2, idx2, sd3, fm3, nullptr, V2, 256, 1, 0);
  // pool2
  {
    int total = B * V3 * 256;
    k_pool<<<(total + 255) / 256, 256, 0, stream>>>(fm3, idx2, sel2, fm3p, V2, V3, 256);
    int tv = B * V3 * 3;
    k_sel_verts<<<(tv + 255) / 256, 256, 0, stream>>>(verts2, sel2, verts3, V2, V3);
  }
  // knn level 3 (VCAND = 256/64 = 4)
  k_knn4<4><<<B * V3 / 4, 256, 0, stream>>>(verts3, idx3, V3);
  // layer4 -> transposed write into d_out
  k_gemm_bias<<<dim3(80, 16), 256, 0, stream>>>(fm3p, W4, b4, fbuf, B * V3, 5120, 256);
  k_conv_layer<<<B * V3, 256, (4 * 1024 + 80) * 4, stream>>>(fbuf, verts3, idx3, sd4, nullptr, out, V3, 1024, 0, 1);
}

// Round 6
// 483.121 us; speedup vs baseline: 2.2025x; 1.0938x over previous
//
#include <hip/hip_runtime.h>
#include <vector>
#include <algorithm>
#include <cstdint>
#include <cstring>
#include <cmath>

// ===================== host-side JAX threefry replication =====================
static inline uint32_t tf_rotl(uint32_t x, int r) { return (x << r) | (x >> (32 - r)); }

static void tf2x32(uint32_t k0, uint32_t k1, uint32_t x0, uint32_t x1,
                   uint32_t* o0, uint32_t* o1) {
  uint32_t ks2 = k0 ^ k1 ^ 0x1BD11BDAu;
  uint32_t v0 = x0 + k0, v1 = x1 + k1;
  static const int R0[4] = {13, 15, 26, 6}, R1[4] = {17, 29, 16, 24};
#define RND4(R) do { for (int i_ = 0; i_ < 4; ++i_) { v0 += v1; v1 = tf_rotl(v1, R[i_]); v1 ^= v0; } } while (0)
  RND4(R0); v0 += k1;  v1 += ks2 + 1u;
  RND4(R1); v0 += ks2; v1 += k0 + 2u;
  RND4(R0); v0 += k0;  v1 += k1 + 3u;
  RND4(R1); v0 += k1;  v1 += ks2 + 4u;
  RND4(R0); v0 += ks2; v1 += k0 + 5u;
#undef RND4
  *o0 = v0; *o1 = v1;
}

static void jax_permutation(uint32_t seed, int n, int rounds, int* x) {
  uint32_t k0 = 0u, k1 = seed;
  for (int i = 0; i < n; ++i) x[i] = i;
  std::vector<uint32_t> bits(n);
  std::vector<int> ord(n), xn(n);
  for (int r = 0; r < rounds; ++r) {
    uint32_t nk0, nk1, sk0, sk1;
    tf2x32(k0, k1, 0u, 0u, &nk0, &nk1);
    tf2x32(k0, k1, 0u, 1u, &sk0, &sk1);
    for (int i = 0; i < n; ++i) {
      uint32_t h, l;
      tf2x32(sk0, sk1, 0u, (uint32_t)i, &h, &l);
      bits[i] = h ^ l;
    }
    for (int i = 0; i < n; ++i) ord[i] = i;
    std::stable_sort(ord.begin(), ord.end(),
                     [&](int a, int b) { return bits[a] < bits[b]; });
    for (int i = 0; i < n; ++i) xn[i] = x[ord[i]];
    memcpy(x, xn.data(), (size_t)n * sizeof(int));
    k0 = nk0; k1 = nk1;
  }
}

// ===================== device kernels =====================
#define NEI 20

__device__ __forceinline__ float san(float v) {
  v = (v != v) ? 0.0f : v;
  return fmaxf(-1e4f, fminf(v, 1e4f));
}

__global__ void k_san_copy(const float* __restrict__ in, float* __restrict__ out, int n) {
  int i = blockIdx.x * blockDim.x + threadIdx.x;
  if (i < n) out[i] = san(in[i]);
}

// normalize all 5 direction matrices in one launch. Segments (3 x E each):
// E = 128,256,512,1024,4096; cumulative 128,384,896,1920,6016
__global__ void k_norm_dirs_all(const float* __restrict__ d0, const float* __restrict__ d1,
                                const float* __restrict__ d2, const float* __restrict__ d3,
                                const float* __restrict__ d4,
                                float* __restrict__ s0, float* __restrict__ s1,
                                float* __restrict__ s2, float* __restrict__ s3,
                                float* __restrict__ s4) {
  int t = blockIdx.x * blockDim.x + threadIdx.x;
  const float* d; float* s; int E, e;
  if (t < 128)       { d = d0; s = s0; E = 128;  e = t; }
  else if (t < 384)  { d = d1; s = s1; E = 256;  e = t - 128; }
  else if (t < 896)  { d = d2; s = s2; E = 512;  e = t - 384; }
  else if (t < 1920) { d = d3; s = s3; E = 1024; e = t - 896; }
  else if (t < 6016) { d = d4; s = s4; E = 4096; e = t - 1920; }
  else return;
  float a = san(d[e]);
  float b = san(d[E + e]);
  float c = san(d[2 * E + e]);
  float nrm = sqrtf(a * a + b * b + c * c);
  float m = fmaxf(nrm, 1e-12f);
  s[e] = a / m; s[E + e] = b / m; s[2 * E + e] = c / m;
}

// KNN v4: one WAVE per query (4 queries/block, no barriers, no LDS).
template <int VCAND>
__global__ __launch_bounds__(256) void k_knn4(const float* __restrict__ verts,
                                              int* __restrict__ nidx, int V) {
  const int wid = threadIdx.x >> 6;
  const int lane = threadIdx.x & 63;
  const int row = blockIdx.x * 4 + wid;
  const int b = row / V, i = row % V;
  const float* vb = verts + (size_t)b * V * 3;
  const float xi = vb[3 * i], yi = vb[3 * i + 1], zi = vb[3 * i + 2];
  const float sqi = xi * xi + yi * yi + zi * zi;

  unsigned long long q0 = ~0ULL, q1 = ~0ULL, q2 = ~0ULL;
#pragma unroll 8
  for (int c = 0; c < VCAND; ++c) {
    int j = c * 64 + lane;
    float xj = vb[3 * j], yj = vb[3 * j + 1], zj = vb[3 * j + 2];
    float sqj = xj * xj + yj * yj + zj * zj;
    float dot = xi * xj + yi * yj + zi * zj;
    float dd = (sqi + sqj) - 2.0f * dot;
    unsigned u = __float_as_uint(dd);
    u ^= (u & 0x80000000u) ? 0xFFFFFFFFu : 0x80000000u;  // total-order map
    unsigned long long k = (((unsigned long long)u) << 32) | (unsigned)j;
    if (k < q2) {
      if (k < q1) {
        q2 = q1;
        if (k < q0) { q1 = q0; q0 = k; } else { q1 = k; }
      } else {
        q2 = k;
      }
    }
  }

  for (int r = 0; r < 21; ++r) {
    unsigned long long m = q0;
#pragma unroll
    for (int o = 1; o < 64; o <<= 1) {
      unsigned long long t = __shfl_xor(m, o);
      if (t < m) m = t;
    }
    if (q0 == m) {
      if (r > 0) nidx[(size_t)row * NEI + (r - 1)] = (int)(m & 0xFFFFFFFFu);
      q0 = q1; q1 = q2; q2 = ~0ULL;
      if (q0 == ~0ULL) {
        unsigned long long nm = ~0ULL;
        for (int c = 0; c < VCAND; ++c) {
          int j = c * 64 + lane;
          float xj = vb[3 * j], yj = vb[3 * j + 1], zj = vb[3 * j + 2];
          float sqj = xj * xj + yj * yj + zj * zj;
          float dot = xi * xj + yi * yj + zi * zj;
          float dd = (sqi + sqj) - 2.0f * dot;
          unsigned u = __float_as_uint(dd);
          u ^= (u & 0x80000000u) ? 0xFFFFFFFFu : 0x80000000u;
          unsigned long long k = (((unsigned long long)u) << 32) | (unsigned)j;
          if (k > m && k < nm) nm = k;
        }
        q0 = nm;
      }
    }
  }
}

// conv_surface: C=32, E=128. One block (128 thr) per (b,v).
__global__ __launch_bounds__(128) void k_conv_surface(const float* __restrict__ verts,
                                                      const int* __restrict__ nidx,
                                                      const float* __restrict__ sd,
                                                      float* __restrict__ fm, int V) {
  int row = blockIdx.x;
  int b = row / V, v = row % V;
  const float* vb = verts + (size_t)b * V * 3;
  __shared__ float nd[60];
  __shared__ float mcol[128];
  int tid = threadIdx.x;
  if (tid < NEI) {
    int j = nidx[(size_t)row * NEI + tid];
    float dx = vb[3 * j] - vb[3 * v];
    float dy = vb[3 * j + 1] - vb[3 * v + 1];
    float dz = vb[3 * j + 2] - vb[3 * v + 2];
    float nrm = sqrtf(dx * dx + dy * dy + dz * dz);
    float m = fmaxf(nrm, 1e-12f);
    nd[tid * 3] = dx / m; nd[tid * 3 + 1] = dy / m; nd[tid * 3 + 2] = dz / m;
  }
  __syncthreads();
  {
    int e = tid;
    float s0 = sd[e], s1 = sd[128 + e], s2 = sd[256 + e];
    float me = 0.0f;
#pragma unroll
    for (int n = 0; n < NEI; ++n) {
      float th = nd[3 * n] * s0 + nd[3 * n + 1] * s1 + nd[3 * n + 2] * s2;
      th = fmaxf(th, 0.0f);
      me = fmaxf(me, th);
    }
    mcol[e] = me;
  }
  __syncthreads();
  if (tid < 32) {
    float o = mcol[tid] + mcol[32 + tid] + mcol[64 + tid] + mcol[96 + tid];
    o = fmaxf(o, 0.0f);
    fm[(size_t)row * 32 + tid] = o;
  }
}

// fp32 tiled GEMM 64x64x16 (guarded; used for layer1): C = A*W + bias
__global__ __launch_bounds__(256) void k_gemm_bias(const float* __restrict__ A,
                                                   const float* __restrict__ W,
                                                   const float* __restrict__ bias,
                                                   float* __restrict__ Cm,
                                                   int M, int N, int K) {
  __shared__ float As[16][68];
  __shared__ float Bs[16][68];
  int n0 = blockIdx.x * 64, m0 = blockIdx.y * 64;
  int tx = threadIdx.x & 15, ty = threadIdx.x >> 4;
  float acc[4][4] = {};
  for (int k0 = 0; k0 < K; k0 += 16) {
    for (int t = threadIdx.x; t < 1024; t += 256) {
      int mm = t >> 4, kk = t & 15;
      int m = m0 + mm;
      As[kk][mm] = (m < M) ? A[(size_t)m * K + (k0 + kk)] : 0.0f;
    }
    for (int t = threadIdx.x; t < 1024; t += 256) {
      int kk = t >> 6, nn = t & 63;
      int n = n0 + nn;
      Bs[kk][nn] = (n < N) ? san(W[(size_t)(k0 + kk) * N + n]) : 0.0f;
    }
    __syncthreads();
#pragma unroll
    for (int kk = 0; kk < 16; ++kk) {
      float4 av = *(const float4*)&As[kk][ty << 2];
      float4 bv = *(const float4*)&Bs[kk][tx << 2];
      float a[4] = {av.x, av.y, av.z, av.w};
      float bb[4] = {bv.x, bv.y, bv.z, bv.w};
#pragma unroll
      for (int i = 0; i < 4; ++i)
#pragma unroll
        for (int j = 0; j < 4; ++j) acc[i][j] += a[i] * bb[j];
    }
    __syncthreads();
  }
  for (int i = 0; i < 4; ++i)
    for (int j = 0; j < 4; ++j) {
      int m = m0 + (ty << 2) + i, n = n0 + (tx << 2) + j;
      if (m < M && n < N) Cm[(size_t)m * N + n] = acc[i][j] + san(bias[n]);
    }
}

// fp32 tiled GEMM 128x128x16, requires M%128==0, N%128==0, K%16==0.
// 256 threads, 8x8 acc/thread; B-frag split tx*4 / 64+tx*4 (2-way banks = free).
__global__ __launch_bounds__(256) void k_gemm128(const float* __restrict__ A,
                                                 const float* __restrict__ W,
                                                 const float* __restrict__ bias,
                                                 float* __restrict__ Cm,
                                                 int M, int N, int K) {
  __shared__ float As[16][132];
  __shared__ float Bs[16][132];
  const int n0 = blockIdx.x * 128, m0 = blockIdx.y * 128;
  const int tx = threadIdx.x & 15, ty = threadIdx.x >> 4;
  const int bm = ty * 8;
  float acc[8][8] = {};
  float bias_lo[4], bias_hi[4];
#pragma unroll
  for (int j = 0; j < 4; ++j) {
    bias_lo[j] = san(bias[n0 + tx * 4 + j]);
    bias_hi[j] = san(bias[n0 + 64 + tx * 4 + j]);
  }
  for (int k0 = 0; k0 < K; k0 += 16) {
    // stage A: 128 rows x 16 k = 512 float4, 2 per thread
#pragma unroll
    for (int r = 0; r < 2; ++r) {
      int t = r * 256 + threadIdx.x;
      int mm = t >> 2, kk = (t & 3) * 4;
      float4 v = *(const float4*)&A[(size_t)(m0 + mm) * K + k0 + kk];
      As[kk + 0][mm] = v.x; As[kk + 1][mm] = v.y; As[kk + 2][mm] = v.z; As[kk + 3][mm] = v.w;
    }
    // stage B: 16 k-rows x 128 n = 512 float4, 2 per thread
#pragma unroll
    for (int r = 0; r < 2; ++r) {
      int t = r * 256 + threadIdx.x;
      int kk = t >> 5, nn = (t & 31) * 4;
      float4 v = *(const float4*)&W[(size_t)(k0 + kk) * N + n0 + nn];
      *(float4*)&Bs[kk][nn] = v;
    }
    __syncthreads();
#pragma unroll
    for (int kk = 0; kk < 16; ++kk) {
      float4 a0 = *(const float4*)&As[kk][bm];
      float4 a1 = *(const float4*)&As[kk][bm + 4];
      float4 b0 = *(const float4*)&Bs[kk][tx * 4];
      float4 b1 = *(const float4*)&Bs[kk][64 + tx * 4];
      float a[8] = {a0.x, a0.y, a0.z, a0.w, a1.x, a1.y, a1.z, a1.w};
      float bb[8] = {b0.x, b0.y, b0.z, b0.w, b1.x, b1.y, b1.z, b1.w};
#pragma unroll
      for (int i = 0; i < 8; ++i)
#pragma unroll
        for (int j = 0; j < 8; ++j) acc[i][j] += a[i] * bb[j];
    }
    __syncthreads();
  }
#pragma unroll
  for (int i = 0; i < 8; ++i) {
    int m = m0 + bm + i;
    float4 lo = {acc[i][0] + bias_lo[0], acc[i][1] + bias_lo[1],
                 acc[i][2] + bias_lo[2], acc[i][3] + bias_lo[3]};
    float4 hi = {acc[i][4] + bias_hi[0], acc[i][5] + bias_hi[1],
                 acc[i][6] + bias_hi[2], acc[i][7] + bias_hi[3]};
    *(float4*)&Cm[(size_t)m * N + n0 + tx * 4] = lo;
    *(float4*)&Cm[(size_t)m * N + n0 + 64 + tx * 4] = hi;
  }
}

// conv layer: out[c] = f[row][c] + sum_s max_n relu(nd_n . sd_e) * f[j_n][C+e]
__global__ __launch_bounds__(256) void k_conv_layer(const float* __restrict__ f,
                                                    const float* __restrict__ verts,
                                                    const int* __restrict__ nidx,
                                                    const float* __restrict__ sd,
                                                    float* __restrict__ outf,
                                                    int V, int C, int relu_out) {
  int row = blockIdx.x;
  int b = row / V, v = row % V;
  int E = 4 * C;
  extern __shared__ float sm[];
  float* mcol = sm;           // E floats
  float* nd = sm + E;         // 60 floats
  int* jr = (int*)(nd + 60);  // 20 ints
  int tid = threadIdx.x;
  const float* vb = verts + (size_t)b * V * 3;
  if (tid < NEI) {
    int j = nidx[(size_t)row * NEI + tid];
    jr[tid] = j;
    float dx = vb[3 * j] - vb[3 * v];
    float dy = vb[3 * j + 1] - vb[3 * v + 1];
    float dz = vb[3 * j + 2] - vb[3 * v + 2];
    float nrm = sqrtf(dx * dx + dy * dy + dz * dz);
    float m = fmaxf(nrm, 1e-12f);
    nd[tid * 3] = dx / m; nd[tid * 3 + 1] = dy / m; nd[tid * 3 + 2] = dz / m;
  }
  __syncthreads();
  size_t fb = (size_t)b * V;
  int fivec = 5 * C;
  for (int e = tid; e < E; e += blockDim.x) {
    float s0 = sd[e], s1 = sd[E + e], s2 = sd[2 * E + e];
    float me = -INFINITY;
#pragma unroll
    for (int n = 0; n < NEI; ++n) {
      float th = nd[3 * n] * s0 + nd[3 * n + 1] * s1 + nd[3 * n + 2] * s2;
      th = fmaxf(th, 0.0f);
      float fv = f[(fb + jr[n]) * (size_t)fivec + C + e];
      me = fmaxf(me, th * fv);
    }
    mcol[e] = me;
  }
  __syncthreads();
  for (int c = tid; c < C; c += blockDim.x) {
    float o = f[(size_t)row * fivec + c] + mcol[c] + mcol[C + c] + mcol[2 * C + c] + mcol[3 * C + c];
    if (relu_out) o = fmaxf(o, 0.0f);
    outf[(size_t)row * C + c] = o;
  }
}

// transpose (B, V, C) -> (B, C, V), 32x32 LDS tiles, coalesced both sides
__global__ __launch_bounds__(256) void k_transpose_vc(const float* __restrict__ in,
                                                      float* __restrict__ out,
                                                      int V, int C) {
  __shared__ float tile[32][33];
  int b = blockIdx.z;
  int c0 = blockIdx.x * 32, v0 = blockIdx.y * 32;
  int tx = threadIdx.x & 31, ty4 = threadIdx.x >> 5;  // 32 x 8
#pragma unroll
  for (int j = 0; j < 4; ++j) {
    int v = v0 + ty4 * 4 + j;
    tile[ty4 * 4 + j][tx] = in[((size_t)b * V + v) * C + c0 + tx];
  }
  __syncthreads();
#pragma unroll
  for (int j = 0; j < 4; ++j) {
    int c = c0 + ty4 * 4 + j;
    out[((size_t)b * C + c) * V + v0 + tx] = tile[tx][ty4 * 4 + j];
  }
}

__global__ void k_pool(const float* __restrict__ fm, const int* __restrict__ nidx,
                       const int* __restrict__ sel, float* __restrict__ outp,
                       int Vin, int Vout, int C) {
  int t = blockIdx.x * blockDim.x + threadIdx.x;
  int total = 4 * Vout * C;
  if (t >= total) return;
  int c = t % C;
  int p = (t / C) % Vout;
  int b = t / (C * Vout);
  int sv = sel[p];
  const int* ir = nidx + ((size_t)b * Vin + sv) * NEI;
  float m = -INFINITY;
#pragma unroll
  for (int n = 0; n < NEI; ++n)
    m = fmaxf(m, fm[((size_t)b * Vin + ir[n]) * C + c]);
  outp[((size_t)b * Vout + p) * C + c] = m;
}

__global__ void k_sel_verts(const float* __restrict__ vin, const int* __restrict__ sel,
                            float* __restrict__ vout, int Vin, int Vout) {
  int t = blockIdx.x * blockDim.x + threadIdx.x;
  int total = 4 * Vout * 3;
  if (t >= total) return;
  int d = t % 3;
  int p = (t / 3) % Vout;
  int b = t / (3 * Vout);
  vout[((size_t)b * Vout + p) * 3 + d] = vin[((size_t)b * Vin + sel[p]) * 3 + d];
}

// ===================== launch =====================
extern "C" void kernel_launch(void* const* d_in, const int* in_sizes, int n_in,
                              void* d_out, int out_size, void* d_ws, size_t ws_size,
                              hipStream_t stream) {
  (void)in_sizes; (void)n_in; (void)out_size; (void)ws_size;
  const int B = 4, V1 = 4096, V2 = 1024, V3 = 256;

  const float* vin   = (const float*)d_in[0];
  const float* dirs0 = (const float*)d_in[1];
  const float* W1 = (const float*)d_in[2];
  const float* b1 = (const float*)d_in[3];
  const float* D1 = (const float*)d_in[4];
  const float* W2 = (const float*)d_in[5];
  const float* b2 = (const float*)d_in[6];
  const float* D2 = (const float*)d_in[7];
  const float* W3 = (const float*)d_in[8];
  const float* b3 = (const float*)d_in[9];
  const float* D3 = (const float*)d_in[10];
  const float* W4 = (const float*)d_in[11];
  const float* b4 = (const float*)d_in[12];
  const float* D4 = (const float*)d_in[13];
  float* out = (float*)d_out;

  char* ws = (char*)d_ws;
  size_t off = 0;
  auto alloc = [&](size_t bytes) -> char* {
    char* p = ws + off;
    off = (off + bytes + 255) & ~(size_t)255;
    return p;
  };
  int* sel1 = (int*)alloc((size_t)V2 * 4);
  int* sel2 = (int*)alloc((size_t)V3 * 4);
  float* verts1 = (float*)alloc((size_t)B * V1 * 3 * 4);
  float* verts2 = (float*)alloc((size_t)B * V2 * 3 * 4);
  float* verts3 = (float*)alloc((size_t)B * V3 * 3 * 4);
  int* idx1 = (int*)alloc((size_t)B * V1 * NEI * 4);
  int* idx2 = (int*)alloc((size_t)B * V2 * NEI * 4);
  int* idx3 = (int*)alloc((size_t)B * V3 * NEI * 4);
  float* sd0 = (float*)alloc(3 * 128 * 4);
  float* sd1 = (float*)alloc(3 * 256 * 4);
  float* sd2 = (float*)alloc(3 * 512 * 4);
  float* sd3 = (float*)alloc(3 * 1024 * 4);
  float* sd4 = (float*)alloc(3 * 4096 * 4);
  float* bufA = (float*)alloc((size_t)B * V1 * 32 * 4);   // fm0 / fm2
  float* bufB = (float*)alloc((size_t)B * V1 * 64 * 4);   // fm1 / fm3 / conv4-out (4MB)
  float* bufC = (float*)alloc((size_t)B * V2 * 64 * 4);   // fm1p / fm3p
  float* fbuf = (float*)alloc((size_t)B * V1 * 320 * 4);
  float* fm0 = bufA, *fm2 = bufA;
  float* fm1 = bufB, *fm3 = bufB;
  float* fm1p = bufC, *fm3p = bufC;
  float* conv4out = bufB;

  static int perm1[4096];
  static int perm2[1024];
  static int selh[1280];
  jax_permutation(42u, 4096, 2, perm1);
  jax_permutation(43u, 1024, 1, perm2);
  memcpy(selh, perm1, 1024 * sizeof(int));
  memcpy(selh + 1024, perm2, 256 * sizeof(int));
  hipMemcpyAsync(sel1, selh, 1024 * sizeof(int), hipMemcpyHostToDevice, stream);
  hipMemcpyAsync(sel2, selh + 1024, 256 * sizeof(int), hipMemcpyHostToDevice, stream);

  {
    int n = B * V1 * 3;
    k_san_copy<<<(n + 255) / 256, 256, 0, stream>>>(vin, verts1, n);
  }
  k_norm_dirs_all<<<24, 256, 0, stream>>>(dirs0, D1, D2, D3, D4, sd0, sd1, sd2, sd3, sd4);
  // knn level 1 (VCAND = 64)
  k_knn4<64><<<B * V1 / 4, 256, 0, stream>>>(verts1, idx1, V1);
  k_conv_surface<<<B * V1, 128, 0, stream>>>(verts1, idx1, sd0, fm0, V1);
  // layer1 (N=320 not /128 -> 64-tile)
  k_gemm_bias<<<dim3(5, 256), 256, 0, stream>>>(fm0, W1, b1, fbuf, B * V1, 320, 32);
  k_conv_layer<<<B * V1, 256, (4 * 64 + 80) * 4, stream>>>(fbuf, verts1, idx1, sd1, fm1, V1, 64, 1);
  // pool1
  {
    int total = B * V2 * 64;
    k_pool<<<(total + 255) / 256, 256, 0, stream>>>(fm1, idx1, sel1, fm1p, V1, V2, 64);
    int tv = B * V2 * 3;
    k_sel_verts<<<(tv + 255) / 256, 256, 0, stream>>>(verts1, sel1, verts2, V1, V2);
  }
  // knn level 2 (VCAND = 16)
  k_knn4<16><<<B * V2 / 4, 256, 0, stream>>>(verts2, idx2, V2);
  // layer2: 4096x640x64
  k_gemm128<<<dim3(640 / 128, 4096 / 128), 256, 0, stream>>>(fm1p, W2, b2, fbuf, B * V2, 640, 64);
  k_conv_layer<<<B * V2, 256, (4 * 128 + 80) * 4, stream>>>(fbuf, verts2, idx2, sd2, fm2, V2, 128, 1);
  // layer3: 4096x1280x128
  k_gemm128<<<dim3(1280 / 128, 4096 / 128), 256, 0, stream>>>(fm2, W3, b3, fbuf, B * V2, 1280, 128);
  k_conv_layer<<<B * V2, 256, (4 * 256 + 80) * 4, stream>>>(fbuf, verts2, idx2, sd3, fm3, V2, 256, 1);
  // pool2
  {
    int total = B * V3 * 256;
    k_pool<<<(total + 255) / 256, 256, 0, stream>>>(fm3, idx2, sel2, fm3p, V2, V3, 256);
    int tv = B * V3 * 3;
    k_sel_verts<<<(tv + 255) / 256, 256, 0, stream>>>(verts2, sel2, verts3, V2, V3);
  }
  // knn level 3 (VCAND = 4)
  k_knn4<4><<<B * V3 / 4, 256, 0, stream>>>(verts3, idx3, V3);
  // layer4: 1024x5120x256, conv C=1024 row-major, then coalesced transpose
  k_gemm128<<<dim3(5120 / 128, 1024 / 128), 256, 0, stream>>>(fm3p, W4, b4, fbuf, B * V3, 5120, 256);
  k_conv_layer<<<B * V3, 256, (4 * 1024 + 80) * 4, stream>>>(fbuf, verts3, idx3, sd4, conv4out, V3, 1024, 0);
  k_transpose_vc<<<dim3(1024 / 32, 256 / 32, B), 256, 0, stream>>>(conv4out, out, V3, 1024);
}